// Round 6
// baseline (414.216 us; speedup 1.0000x reference)
//
#include <hip/hip_runtime.h>
#include <cmath>

typedef unsigned short u16;
typedef unsigned int u32;
typedef __bf16 bf16x8 __attribute__((ext_vector_type(8)));
typedef float f32x4 __attribute__((ext_vector_type(4)));

#define SEQ 2048
#define EMB 1024
#define NHEAD 16
#define HDIM 64
#define FFDIM 4096
#define NBATCH 2
#define QKVLD 3072  // fused QKV row stride
#define PWS 68      // attn Pw row stride (u16)

// Q pre-scale folds 1/sqrt(64) and 1/ln(2) so softmax uses exp2 directly.
#define QSCALE 0.18033688011112042f

__device__ __forceinline__ u16 f2bf(float f) {
  u32 u = __float_as_uint(f);
  u32 r = u + 0x7fffu + ((u >> 16) & 1u);
  return (u16)(r >> 16);
}

__device__ __forceinline__ float ex2(float x) {
#if __has_builtin(__builtin_amdgcn_exp2f)
  return __builtin_amdgcn_exp2f(x);
#else
  return exp2f(x);
#endif
}

// tanh-form GELU via a single exp2: gelu(x) = x * sigmoid(2u),
// u = 0.7978845608*(x + 0.044715 x^3).  max |err| vs exact erf ~3e-3.
__device__ __forceinline__ float geluf(float x) {
  float u = 0.7978845608028654f * (x + 0.044715f * x * x * x);
  float e = ex2(2.8853900817779268f * u);  // exp(2u)
  return x - x / (e + 1.0f);
}

// async global->LDS, 16B per lane. LDS dest must be wave-uniform base + lane*16.
__device__ __forceinline__ void gload16(const void* g, void* l) {
  __builtin_amdgcn_global_load_lds(
      (const __attribute__((address_space(1))) unsigned int*)g,
      (__attribute__((address_space(3))) unsigned int*)l, 16, 0, 0);
}

// 32-bit LDS byte address for inline-asm ds ops.
__device__ __forceinline__ u32 lds_addr(const void* p) {
  return (u32)(size_t)(const __attribute__((address_space(3))) void*)p;
}

// Inline-asm ds_read_b128: invisible to the compiler's waitcnt-insertion pass.
// Caller supplies ordering: counted vmcnt + barrier for RAW, and an explicit
// s_waitcnt lgkmcnt(0) + sched_barrier(0) before consuming (rule #18).
template <int IMM>
__device__ __forceinline__ bf16x8 dsr16(u32 a) {
  bf16x8 r;
  asm volatile("ds_read_b128 %0, %1 offset:%2" : "=v"(r) : "v"(a), "n"(IMM));
  return r;
}

// XCD-chunked bijective blockIdx swizzle (T1).  lin%8 ~ XCD on MI355X; give
// each XCD a CONTIGUOUS chunk of the row-major grid.  Requires nwg % 8 == 0.
__device__ __forceinline__ void xcd_swizzle(int gx, int gy, int& bx, int& by) {
  int nwg = gx * gy;
  int lin = blockIdx.x + gx * blockIdx.y;
  int q = nwg >> 3;
  int nl = (lin & 7) * q + (lin >> 3);
  bx = nl % gx;
  by = nl / gx;
}

// ---------------- weight transpose + fp32->bf16 ----------------
// W [K,N] fp32 -> WT [N,K] bf16 (generic, for W1/W2)
__global__ __launch_bounds__(256)
void wtrans_kernel(const float* __restrict__ W, u16* __restrict__ WT, int K, int N) {
  __shared__ float tile[32][33];
  int tx = threadIdx.x & 31, ty = threadIdx.x >> 5;
  int n0 = blockIdx.x * 32, k0 = blockIdx.y * 32;
#pragma unroll
  for (int i = 0; i < 32; i += 8)
    tile[ty + i][tx] = W[(size_t)(k0 + ty + i) * N + (n0 + tx)];
  __syncthreads();
#pragma unroll
  for (int i = 0; i < 32; i += 8)
    WT[(size_t)(n0 + ty + i) * K + (k0 + tx)] = f2bf(tile[tx][ty + i]);
}

// 4 square [1024x1024] weights in one dispatch: z=0..2 -> WqkvT rows, z=3 -> WoT
__global__ __launch_bounds__(256)
void wtrans4_kernel(const float* __restrict__ W0, const float* __restrict__ W1_,
                    const float* __restrict__ W2_, const float* __restrict__ W3,
                    u16* __restrict__ Dqkv, u16* __restrict__ Do) {
  __shared__ float tile[32][33];
  int z = blockIdx.z;
  const float* W = (z == 0) ? W0 : (z == 1) ? W1_ : (z == 2) ? W2_ : W3;
  u16* D = (z < 3) ? (Dqkv + (size_t)z * EMB * EMB) : Do;
  int tx = threadIdx.x & 31, ty = threadIdx.x >> 5;
  int n0 = blockIdx.x * 32, k0 = blockIdx.y * 32;
#pragma unroll
  for (int i = 0; i < 32; i += 8)
    tile[ty + i][tx] = W[(size_t)(k0 + ty + i) * EMB + (n0 + tx)];
  __syncthreads();
#pragma unroll
  for (int i = 0; i < 32; i += 8)
    D[(size_t)(n0 + ty + i) * EMB + (k0 + tx)] = f2bf(tile[tx][ty + i]);
}

// ---------------- V transpose per head: QKV [B*S,3072] (V at col 2048+h*64)
// -> Vt [B*H, 64, SEQ]
__global__ __launch_bounds__(256)
void vtrans_kernel(const u16* __restrict__ QKV, u16* __restrict__ Vt) {
  __shared__ u16 tile[64 * 72];
  int bh = blockIdx.y, b = bh >> 4, h = bh & 15;
  int s0 = blockIdx.x * 64;
  const u16* src = QKV + (size_t)b * SEQ * QKVLD + 2048 + (size_t)h * HDIM;
  int tid = threadIdx.x;
#pragma unroll
  for (int cc = 0; cc < 2; ++cc) {
    int c = tid + cc * 256;
    int s = c >> 3, d0 = (c & 7) * 8;
    uint4 v = *(const uint4*)(src + (size_t)(s0 + s) * QKVLD + d0);
    *(uint4*)(&tile[s * 72 + d0]) = v;
  }
  __syncthreads();
  u16* dst = Vt + (size_t)bh * HDIM * SEQ;
#pragma unroll
  for (int cc = 0; cc < 2; ++cc) {
    int c = tid + cc * 256;
    int d = c >> 3, t0l = (c & 7) * 8;
    union { uint4 u; u16 s[8]; } ou;
#pragma unroll
    for (int j = 0; j < 8; ++j) ou.s[j] = tile[(t0l + j) * 72 + d];
    *(uint4*)(dst + (size_t)d * SEQ + s0 + t0l) = ou.u;
  }
}

// ---------------- layernorm: 1 row per wave, 4 rows per block ----------------
__global__ __launch_bounds__(256)
void ln_kernel(const float* __restrict__ in, const float* __restrict__ gamma,
               const float* __restrict__ beta, u16* __restrict__ outb) {
  int w = threadIdx.x >> 6, lane = threadIdx.x & 63;
  int row = blockIdx.x * 4 + w;
  size_t base = (size_t)row * EMB;
  float4 v[4];
  float s = 0.f, q = 0.f;
#pragma unroll
  for (int j = 0; j < 4; ++j) {
    v[j] = *(const float4*)(in + base + j * 256 + lane * 4);
    s += v[j].x + v[j].y + v[j].z + v[j].w;
    q += v[j].x * v[j].x + v[j].y * v[j].y + v[j].z * v[j].z + v[j].w * v[j].w;
  }
#pragma unroll
  for (int off = 1; off < 64; off <<= 1) {
    s += __shfl_xor(s, off);
    q += __shfl_xor(q, off);
  }
  float mean = s * (1.0f / EMB);
  float var = q * (1.0f / EMB) - mean * mean;
  float rstd = rsqrtf(var + 1e-5f);
#pragma unroll
  for (int j = 0; j < 4; ++j) {
    int c = j * 256 + lane * 4;
    float4 g4 = *(const float4*)(gamma + c);
    float4 b4 = *(const float4*)(beta + c);
    ushort4 ob;
    ob.x = f2bf((v[j].x - mean) * rstd * g4.x + b4.x);
    ob.y = f2bf((v[j].y - mean) * rstd * g4.y + b4.y);
    ob.z = f2bf((v[j].z - mean) * rstd * g4.z + b4.z);
    ob.w = f2bf((v[j].w - mean) * rstd * g4.w + b4.w);
    *(ushort4*)(outb + base + c) = ob;
  }
}

// ---------------- LN2 fused with Wo split-K reduce ----------------
// in = p[0]+p[pstride]+bias(col)+resid; layernorm(in) -> bf16 + fp32
__global__ __launch_bounds__(256)
void ln2f_kernel(const float* __restrict__ p, size_t pstride,
                 const float* __restrict__ bias, const float* __restrict__ resid,
                 const float* __restrict__ gamma, const float* __restrict__ beta,
                 u16* __restrict__ outb, float* __restrict__ outf) {
  int w = threadIdx.x >> 6, lane = threadIdx.x & 63;
  int row = blockIdx.x * 4 + w;
  size_t base = (size_t)row * EMB;
  float4 v[4];
  float s = 0.f, q = 0.f;
#pragma unroll
  for (int j = 0; j < 4; ++j) {
    int c = j * 256 + lane * 4;
    float4 a = *(const float4*)(p + base + c);
    float4 b = *(const float4*)(p + pstride + base + c);
    float4 r = *(const float4*)(resid + base + c);
    float4 bb = *(const float4*)(bias + c);
    v[j].x = a.x + b.x + r.x + bb.x;
    v[j].y = a.y + b.y + r.y + bb.y;
    v[j].z = a.z + b.z + r.z + bb.z;
    v[j].w = a.w + b.w + r.w + bb.w;
    s += v[j].x + v[j].y + v[j].z + v[j].w;
    q += v[j].x * v[j].x + v[j].y * v[j].y + v[j].z * v[j].z + v[j].w * v[j].w;
  }
#pragma unroll
  for (int off = 1; off < 64; off <<= 1) {
    s += __shfl_xor(s, off);
    q += __shfl_xor(q, off);
  }
  float mean = s * (1.0f / EMB);
  float var = q * (1.0f / EMB) - mean * mean;
  float rstd = rsqrtf(var + 1e-5f);
#pragma unroll
  for (int j = 0; j < 4; ++j) {
    int c = j * 256 + lane * 4;
    float4 g4 = *(const float4*)(gamma + c);
    float4 b4 = *(const float4*)(beta + c);
    float y0 = (v[j].x - mean) * rstd * g4.x + b4.x;
    float y1 = (v[j].y - mean) * rstd * g4.y + b4.y;
    float y2 = (v[j].z - mean) * rstd * g4.z + b4.z;
    float y3 = (v[j].w - mean) * rstd * g4.w + b4.w;
    ushort4 ob;
    ob.x = f2bf(y0); ob.y = f2bf(y1); ob.z = f2bf(y2); ob.w = f2bf(y3);
    *(ushort4*)(outb + base + c) = ob;
    *(float4*)(outf + base + c) = make_float4(y0, y1, y2, y3);
  }
}

// ---------------- split-K reduce: out = p[z0]+p[z1]+bias+resid (fp32) --------
__global__ __launch_bounds__(256)
void reduce2_kernel(const float* __restrict__ p, size_t pstride,
                    const float* __restrict__ bias, const float* __restrict__ resid,
                    float* __restrict__ out, int ncols) {
  size_t i = ((size_t)blockIdx.x * 256 + threadIdx.x) * 4;
  float4 a = *(const float4*)(p + i);
  float4 b = *(const float4*)(p + pstride + i);
  float4 r = *(const float4*)(resid + i);
  int col = (int)(i & (size_t)(ncols - 1));
  float4 bb = *(const float4*)(bias + col);
  float4 o;
  o.x = a.x + b.x + r.x + bb.x;
  o.y = a.y + b.y + r.y + bb.y;
  o.z = a.z + b.z + r.z + bb.z;
  o.w = a.w + b.w + r.w + bb.w;
  *(float4*)(out + i) = o;
}

// ---------------- GEMM (round-0 structure): C[M,N] = A*BT^T, 128x128 tile ----
// 256 threads, 32KB LDS -> 4 resident blocks/CU; per-K-step full drain is
// hidden by cross-block overlap (m114 mechanism).  + XCD-chunked swizzle.
__global__ __launch_bounds__(256)
void gemm_bt(const u16* __restrict__ A, const u16* __restrict__ BT,
             const float* __restrict__ bias, const float* __restrict__ bias2,
             const float* __restrict__ bias3, void* __restrict__ out,
             const float* __restrict__ resid, int M, int N, int K,
             int mode, float scale, int ksplit,
             float* __restrict__ partial, size_t pstride) {
  __shared__ __align__(16) u16 As[128 * 64];
  __shared__ __align__(16) u16 Bs[128 * 64];
  int tid = threadIdx.x;
  int lane = tid & 63, w = tid >> 6;
  int wm = w >> 1, wn = w & 1;
  int g = lane >> 4, lr = lane & 15;
  int bx, by;
  xcd_swizzle(gridDim.x, gridDim.y, bx, by);
  int m0 = by * 128, n0 = bx * 128;
  int z = blockIdx.z;
  int kbeg = z * ksplit, kend = kbeg + ksplit;

  f32x4 acc[4][4];
#pragma unroll
  for (int mt = 0; mt < 4; ++mt)
#pragma unroll
    for (int nt = 0; nt < 4; ++nt) {
      acc[mt][nt][0] = 0.f; acc[mt][nt][1] = 0.f;
      acc[mt][nt][2] = 0.f; acc[mt][nt][3] = 0.f;
    }

  size_t ao[4], bo_[4];
  int lo[4];
#pragma unroll
  for (int cc = 0; cc < 4; ++cc) {
    int c = tid + cc * 256;
    int row = c >> 3, slot = c & 7;
    int gc = slot ^ (row & 7);
    ao[cc] = (size_t)(m0 + row) * K + gc * 8;
    bo_[cc] = (size_t)(n0 + row) * K + gc * 8;
    lo[cc] = c * 8;
  }
  int swz[2];
#pragma unroll
  for (int kk = 0; kk < 2; ++kk) swz[kk] = ((kk * 4 + g) ^ (lr & 7)) * 8;

  for (int k0 = kbeg; k0 < kend; k0 += 64) {
    __syncthreads();
#pragma unroll
    for (int cc = 0; cc < 4; ++cc) gload16(A + ao[cc] + k0, As + lo[cc]);
#pragma unroll
    for (int cc = 0; cc < 4; ++cc) gload16(BT + bo_[cc] + k0, Bs + lo[cc]);
    __syncthreads();
#pragma unroll
    for (int kk = 0; kk < 2; ++kk) {
      bf16x8 af[4], bfr[4];
#pragma unroll
      for (int mt = 0; mt < 4; ++mt)
        af[mt] = *(const bf16x8*)(As + (wm * 64 + mt * 16 + lr) * 64 + swz[kk]);
#pragma unroll
      for (int nt = 0; nt < 4; ++nt)
        bfr[nt] = *(const bf16x8*)(Bs + (wn * 64 + nt * 16 + lr) * 64 + swz[kk]);
#pragma unroll
      for (int mt = 0; mt < 4; ++mt)
#pragma unroll
        for (int nt = 0; nt < 4; ++nt)
          acc[mt][nt] = __builtin_amdgcn_mfma_f32_16x16x32_bf16(af[mt], bfr[nt], acc[mt][nt], 0, 0, 0);
    }
  }

  float* pz = partial + (size_t)z * pstride;
#pragma unroll
  for (int mt = 0; mt < 4; ++mt) {
    int row = m0 + wm * 64 + mt * 16 + g * 4;
#pragma unroll
    for (int nt = 0; nt < 4; ++nt) {
      int col = n0 + wn * 64 + nt * 16 + lr;
      float bcol;
      if (mode == 3) {
        int which = col >> 10;
        const float* bp = (which == 0) ? bias : (which == 1) ? bias2 : bias3;
        bcol = bp[col & 1023];
      } else if (mode != 4) {
        bcol = bias[col];
      } else {
        bcol = 0.f;
      }
#pragma unroll
      for (int r = 0; r < 4; ++r) {
        float vacc = acc[mt][nt][r] + bcol;
        size_t idx = (size_t)(row + r) * N + col;
        if (mode == 0)      ((u16*)out)[idx] = f2bf(vacc * scale);
        else if (mode == 1) ((u16*)out)[idx] = f2bf(geluf(vacc));
        else if (mode == 2) ((float*)out)[idx] = vacc + resid[idx];
        else if (mode == 3) ((u16*)out)[idx] = f2bf(col < 1024 ? vacc * QSCALE : vacc);
        else                pz[idx] = vacc;
      }
    }
  }
}

// ====================================================================
// gemm8<BM>: BMx256 tile, BK=64, 512 threads (8 waves, 2M x 4N),
// 8-phase / 2-K-tile pipelined K-loop with counted vmcnt, asm ds_reads,
// XCD-chunked swizzle.  FROZEN this round (control group).
// ====================================================================

#define BARM __builtin_amdgcn_s_barrier()
#define VMWS asm volatile("s_waitcnt vmcnt(%0)" ::"n"(4 + RA))
#define VMW0 asm volatile("s_waitcnt vmcnt(0)")
#define NOSTG ((void)0)
#define NOWT ((void)0)

#define STG_A(t, d, kh)                                                       \
  { _Pragma("unroll")                                                         \
    for (int j = 0; j < RA; ++j)                                              \
      gload16(A + (size_t)sgA[j] + kbeg + (t) * 64 + (kh) * 32,               \
              As + ((d) * 2 + (kh)) * ABUF + slA[j]); }

#define STG_B(t, d, kh)                                                       \
  { _Pragma("unroll")                                                         \
    for (int j = 0; j < 2; ++j)                                               \
      gload16(BT + (size_t)sgB[j] + kbeg + (t) * 64 + (kh) * 32,              \
              Bs + ((d) * 2 + (kh)) * 8192 + slB[j]); }

#define PHASE(d, kk, mh, STAGE, WAITC)                                        \
  {                                                                           \
    const u32 bA = bB + ((d) * 2 + (kk)) * 16384;                             \
    const u32 aA = aB + ((d) * 2 + (kk)) * (ABUF * 2);                        \
    if ((mh) == 0) {                                                          \
      bfr[0] = dsr16<0>(bA);                                                  \
      bfr[1] = dsr16<1024>(bA);                                               \
      bfr[2] = dsr16<2048>(bA);                                               \
      bfr[3] = dsr16<3072>(bA);                                               \
    }                                                                         \
    bf16x8 af[MT2];                                                           \
    af[0] = dsr16<(((mh) * MT2 + 0) * 1024)>(aA);                             \
    af[1] = dsr16<(((mh) * MT2 + 1) * 1024)>(aA);                             \
    if constexpr (MT2 > 2) {                                                  \
      af[2] = dsr16<(((mh) * MT2 + 2) * 1024)>(aA);                           \
      af[3] = dsr16<(((mh) * MT2 + 3) * 1024)>(aA);                           \
    }                                                                         \
    STAGE;                                                                    \
    BARM;                                                                     \
    asm volatile("s_waitcnt lgkmcnt(0)");                                     \
    __builtin_amdgcn_sched_barrier(0);                                        \
    __builtin_amdgcn_s_setprio(1);                                            \
    _Pragma("unroll")                                                         \
    for (int mi = 0; mi < MT2; ++mi)                                          \
      _Pragma("unroll")                                                       \
      for (int nt = 0; nt < 4; ++nt)                                          \
        acc[(mh) * MT2 + mi][nt] = __builtin_amdgcn_mfma_f32_16x16x32_bf16(   \
            af[mi], bfr[nt], acc[(mh) * MT2 + mi][nt], 0, 0, 0);              \
    __builtin_amdgcn_s_setprio(0);                                            \
    WAITC;                                                                    \
    BARM;                                                                     \
  }

// shared epilogue
#define GEMM_EPILOGUE                                                         \
  float* pz = partial + (size_t)z * pstride;                                  \
  _Pragma("unroll")                                                           \
  for (int mt = 0; mt < MT; ++mt) {                                           \
    int row = m0 + wm * (BM / 2) + mt * 16 + g * 4;                           \
    _Pragma("unroll")                                                         \
    for (int nt = 0; nt < 4; ++nt) {                                          \
      int col = n0 + wn * 64 + nt * 16 + lr;                                  \
      float bcol;                                                             \
      if (mode == 3) {                                                        \
        int which = col >> 10;                                                \
        const float* bp = (which == 0) ? bias : (which == 1) ? bias2 : bias3; \
        bcol = bp[col & 1023];                                                \
      } else if (mode != 4) {                                                 \
        bcol = bias[col];                                                     \
      } else {                                                                \
        bcol = 0.f;                                                           \
      }                                                                       \
      _Pragma("unroll")                                                       \
      for (int r = 0; r < 4; ++r) {                                           \
        float vacc = acc[mt][nt][r] + bcol;                                   \
        size_t idx = (size_t)(row + r) * N + col;                             \
        if (mode == 0)      ((u16*)out)[idx] = f2bf(vacc * scale);            \
        else if (mode == 1) ((u16*)out)[idx] = f2bf(geluf(vacc));             \
        else if (mode == 2) ((float*)out)[idx] = vacc + resid[idx];           \
        else if (mode == 3) ((u16*)out)[idx] = f2bf(col < 1024 ? vacc * QSCALE : vacc); \
        else                pz[idx] = vacc;                                   \
      }                                                                       \
    }                                                                         \
  }

#define GEMM_PRELUDE                                                          \
  constexpr int MT = BM / 32;                                                 \
  constexpr int MT2 = MT / 2;                                                 \
  constexpr int RA = BM / 128;                                                \
  constexpr int ABUF = BM * 32;                                               \
  __shared__ __align__(16) u16 As[4 * ABUF];                                  \
  __shared__ __align__(16) u16 Bs[4 * 8192];                                  \
  int tid = threadIdx.x;                                                      \
  int lane = tid & 63, w = tid >> 6;                                          \
  int wm = w >> 2, wn = w & 3;                                                \
  int g = lane >> 4, lr = lane & 15;                                          \
  int bx, by;                                                                 \
  xcd_swizzle(gridDim.x, gridDim.y, bx, by);                                  \
  int m0 = by * BM, n0 = bx * 256;                                            \
  int z = blockIdx.z;                                                         \
  size_t kbeg = (size_t)z * ksplit;                                           \
  int nk = ksplit >> 6;                                                       \
  int phys = ((lr & 1) * 4 + g) ^ ((lr >> 1) & 7);                            \
  int aoff = wm * (BM / 2) * 32 + (lr >> 1) * 64 + phys * 8;                  \
  int boff = wn * 2048 + (lr >> 1) * 64 + phys * 8;                           \
  const u32 aB = lds_addr(As) + 2 * aoff;                                     \
  const u32 bB = lds_addr(Bs) + 2 * boff;                                     \
  int sgA[RA], slA[RA];                                                       \
  _Pragma("unroll")                                                           \
  for (int j = 0; j < RA; ++j) {                                              \
    int c = tid + j * 512;                                                    \
    int sr = c >> 3, ph = c & 7, l = ph ^ (sr & 7);                           \
    sgA[j] = (m0 + 2 * sr + (l >> 2)) * K + (l & 3) * 8;                      \
    slA[j] = c * 8;                                                           \
  }                                                                           \
  int sgB[2], slB[2];                                                         \
  _Pragma("unroll")                                                           \
  for (int j = 0; j < 2; ++j) {                                               \
    int c = tid + j * 512;                                                    \
    int sr = c >> 3, ph = c & 7, l = ph ^ (sr & 7);                           \
    sgB[j] = (n0 + 2 * sr + (l >> 2)) * K + (l & 3) * 8;                      \
    slB[j] = c * 8;                                                           \
  }                                                                           \
  f32x4 acc[MT][4];                                                           \
  _Pragma("unroll")                                                           \
  for (int mt = 0; mt < MT; ++mt)                                             \
    _Pragma("unroll")                                                         \
    for (int nt = 0; nt < 4; ++nt) {                                          \
      acc[mt][nt][0] = 0.f; acc[mt][nt][1] = 0.f;                             \
      acc[mt][nt][2] = 0.f; acc[mt][nt][3] = 0.f;                             \
    }                                                                         \
  bf16x8 bfr[4];

// gemm8<BM>: 8-phase ring
template <int BM>
__global__ __launch_bounds__(512, 2)
void gemm8(const u16* __restrict__ A, const u16* __restrict__ BT,
           const float* __restrict__ bias, const float* __restrict__ bias2,
           const float* __restrict__ bias3, void* __restrict__ out,
           const float* __restrict__ resid, int M, int N, int K,
           int mode, float scale, int ksplit,
           float* __restrict__ partial, size_t pstride) {
  GEMM_PRELUDE
  int npair = nk >> 1;

  STG_B(0, 0, 0); STG_A(0, 0, 0); STG_B(0, 0, 1); STG_A(0, 0, 1);
  STG_B(1, 1, 0); STG_A(1, 1, 0); STG_B(1, 1, 1);
  VMWS; BARM;

  for (int it = 0; it < npair - 1; ++it) {
    int t1 = 2 * it + 1, t2 = 2 * it + 2, t3 = 2 * it + 3;
    PHASE(0, 0, 0, STG_A(t1, 1, 1), NOWT)
    PHASE(0, 0, 1, STG_B(t2, 0, 0), NOWT)
    PHASE(0, 1, 0, STG_A(t2, 0, 0), NOWT)
    PHASE(0, 1, 1, STG_B(t2, 0, 1), VMWS)
    PHASE(1, 0, 0, STG_A(t2, 0, 1), NOWT)
    PHASE(1, 0, 1, STG_B(t3, 1, 0), NOWT)
    PHASE(1, 1, 0, STG_A(t3, 1, 0), NOWT)
    PHASE(1, 1, 1, STG_B(t3, 1, 1), VMWS)
  }
  {
    int t1 = nk - 1;
    PHASE(0, 0, 0, STG_A(t1, 1, 1), NOWT)
    PHASE(0, 0, 1, NOSTG, NOWT)
    PHASE(0, 1, 0, NOSTG, NOWT)
    PHASE(0, 1, 1, NOSTG, VMW0)
    PHASE(1, 0, 0, NOSTG, NOWT)
    PHASE(1, 0, 1, NOSTG, NOWT)
    PHASE(1, 1, 0, NOSTG, NOWT)
    PHASE(1, 1, 1, NOSTG, NOWT)
  }
  GEMM_EPILOGUE
}

// ---------------- flash attention, paired q-tiles, no-max exp2 softmax -------
// ROUND-6: double-buffered K/V staging (T3-minimum / T14).  Old structure
// paid a full vmcnt(0) drain (~HBM latency) per K/V tile via __syncthreads.
// Now: issue next tile's 4 gload16 at iter top, counted vmcnt(4) waits only
// for the CURRENT tile's (older) 4 loads, raw barrier, compute, barrier.
// LDS 50 KB -> >=3 blocks/CU (grid is 2/CU).
__shared__ __align__(16) u16 attn_Kt[2][64 * 64];
__shared__ __align__(16) u16 attn_VT[2][64 * 64];
__shared__ __align__(16) u16 attn_Pw[2][4][16 * PWS];

template <int S0>
__device__ __forceinline__ void attn_tile(
    int t0, const int* q0, int w, int g, int lr, const bf16x8& ones,
    const u16* __restrict__ Kt, const u16* __restrict__ VT,
    bf16x8 (&qf)[2][2], f32x4 (&lacc)[2], f32x4 (&oacc)[2][4]) {
  f32x4 sacc[2][4];
#pragma unroll
  for (int s = S0; s < 2; ++s)
#pragma unroll
    for (int nt = 0; nt < 4; ++nt) {
      sacc[s][nt][0] = 0.f; sacc[s][nt][1] = 0.f;
      sacc[s][nt][2] = 0.f; sacc[s][nt][3] = 0.f;
    }
#pragma unroll
  for (int kk = 0; kk < 2; ++kk)
#pragma unroll
    for (int nt = 0; nt < 4; ++nt) {
      int sw = ((kk * 4 + g) ^ lr) & 7;
      bf16x8 bfr = *(const bf16x8*)(&Kt[(nt * 16 + lr) * 64 + sw * 8]);
      if (S0 == 0)
        sacc[0][nt] = __builtin_amdgcn_mfma_f32_16x16x32_bf16(qf[0][kk], bfr, sacc[0][nt], 0, 0, 0);
      sacc[1][nt] = __builtin_amdgcn_mfma_f32_16x16x32_bf16(qf[1][kk], bfr, sacc[1][nt], 0, 0, 0);
    }

#pragma unroll
  for (int s = S0; s < 2; ++s) {
    bool diag = (t0 == q0[s]);  // wave-uniform
#pragma unroll
    for (int r = 0; r < 4; ++r) {
#pragma unroll
      for (int nt = 0; nt < 4; ++nt) {
        float pv = ex2(sacc[s][nt][r]);
        if (diag && (nt * 16 + lr > w * 16 + g * 4 + r)) pv = 0.f;
        attn_Pw[s][w][(g * 4 + r) * PWS + nt * 16 + lr] = f2bf(pv);
      }
    }
  }

#pragma unroll
  for (int kk = 0; kk < 2; ++kk) {
    bf16x8 pf0, pf1;
    if (S0 == 0) pf0 = *(const bf16x8*)(&attn_Pw[0][w][lr * PWS + kk * 32 + g * 8]);
    pf1 = *(const bf16x8*)(&attn_Pw[1][w][lr * PWS + kk * 32 + g * 8]);
#pragma unroll
    for (int nt = 0; nt < 4; ++nt) {
      int sw = ((kk * 4 + g) ^ lr) & 7;
      bf16x8 vf = *(const bf16x8*)(&VT[(nt * 16 + lr) * 64 + sw * 8]);
      if (S0 == 0)
        oacc[0][nt] = __builtin_amdgcn_mfma_f32_16x16x32_bf16(pf0, vf, oacc[0][nt], 0, 0, 0);
      oacc[1][nt] = __builtin_amdgcn_mfma_f32_16x16x32_bf16(pf1, vf, oacc[1][nt], 0, 0, 0);
    }
    if (S0 == 0)
      lacc[0] = __builtin_amdgcn_mfma_f32_16x16x32_bf16(pf0, ones, lacc[0], 0, 0, 0);
    lacc[1] = __builtin_amdgcn_mfma_f32_16x16x32_bf16(pf1, ones, lacc[1], 0, 0, 0);
  }
}

__global__ __launch_bounds__(256)
void attn2_kernel(const u16* __restrict__ QKV, const u16* __restrict__ Vt,
                  u16* __restrict__ ctx) {
  int tid = threadIdx.x, lane = tid & 63, w = tid >> 6;
  int g = lane >> 4, lr = lane & 15;
  int bh = blockIdx.y, b = bh >> 4, h = bh & 15;
  int q0[2];
  q0[0] = blockIdx.x * 64;
  q0[1] = (SEQ / 64 - 1 - blockIdx.x) * 64;
  const u16* Qh = QKV + (size_t)b * SEQ * QKVLD + (size_t)h * HDIM;
  const u16* Kh = Qh + 1024;
  const u16* Vth = Vt + (size_t)bh * HDIM * SEQ;

  bf16x8 ones;
#pragma unroll
  for (int j = 0; j < 8; ++j) ones[j] = (__bf16)1.0f;

  bf16x8 qf[2][2];
#pragma unroll
  for (int s = 0; s < 2; ++s)
#pragma unroll
    for (int kk = 0; kk < 2; ++kk)
      qf[s][kk] = *(const bf16x8*)(Qh + (size_t)(q0[s] + w * 16 + lr) * QKVLD + kk * 32 + g * 8);

  f32x4 lacc[2];
  f32x4 oacc[2][4];
#pragma unroll
  for (int s = 0; s < 2; ++s) {
    lacc[s][0] = 0.f; lacc[s][1] = 0.f; lacc[s][2] = 0.f; lacc[s][3] = 0.f;
#pragma unroll
    for (int nt = 0; nt < 4; ++nt) {
      oacc[s][nt][0] = 0.f; oacc[s][nt][1] = 0.f;
      oacc[s][nt][2] = 0.f; oacc[s][nt][3] = 0.f;
    }
  }

  int c1 = tid, c2 = tid + 256;
  int t1 = c1 >> 3, ch1 = (c1 ^ t1) & 7;
  int t2 = c2 >> 3, ch2 = (c2 ^ t2) & 7;

  // stage K/V tile at t0 into buffer buf (4 gload16 per thread)
  auto stage = [&](int buf, int t0) {
    u16* KtB = attn_Kt[buf];
    u16* VTB = attn_VT[buf];
    gload16(Kh + (size_t)(t0 + t1) * QKVLD + ch1 * 8, KtB + c1 * 8);
    gload16(Kh + (size_t)(t0 + t2) * QKVLD + ch2 * 8, KtB + c2 * 8);
    gload16(Vth + (size_t)t1 * SEQ + t0 + ch1 * 8, VTB + c1 * 8);
    gload16(Vth + (size_t)t2 * SEQ + t0 + ch2 * 8, VTB + c2 * 8);
  };

  int niter = (q0[1] >> 6) + 1;
  stage(0, 0);
  int cur = 0;
  for (int it = 0; it < niter; ++it) {
    int t0 = it << 6;
    if (it + 1 < niter) {
      stage(cur ^ 1, t0 + 64);                 // 4 newer loads in flight
      asm volatile("s_waitcnt vmcnt(4)");      // wait only for cur's 4 loads
    } else {
      asm volatile("s_waitcnt vmcnt(0)");
    }
    __builtin_amdgcn_s_barrier();              // all waves' cur loads landed

    if (t0 <= q0[0])
      attn_tile<0>(t0, q0, w, g, lr, ones, attn_Kt[cur], attn_VT[cur], qf, lacc, oacc);
    else
      attn_tile<1>(t0, q0, w, g, lr, ones, attn_Kt[cur], attn_VT[cur], qf, lacc, oacc);

    __builtin_amdgcn_s_barrier();              // readers done before cur is overwritten
    cur ^= 1;
  }

#pragma unroll
  for (int s = 0; s < 2; ++s) {
    int srow = q0[s] + w * 16 + g * 4;
    float inv[4];
#pragma unroll
    for (int r = 0; r < 4; ++r) inv[r] = 1.0f / lacc[s][r];
#pragma unroll
    for (int nt = 0; nt < 4; ++nt) {
      int col = h * HDIM + nt * 16 + lr;
#pragma unroll
      for (int r = 0; r < 4; ++r) {
        float o = oacc[s][nt][r] * inv[r];
        ctx[((size_t)b * SEQ + srow + r) * EMB + col] = f2bf(o);
      }
    }
  }
}

// ---------------- launch ----------------
extern "C" void kernel_launch(void* const* d_in, const int* in_sizes, int n_in,
                              void* d_out, int out_size, void* d_ws, size_t ws_size,
                              hipStream_t stream) {
  const float* x    = (const float*)d_in[0];
  const float* Wq   = (const float*)d_in[2];
  const float* bq   = (const float*)d_in[3];
  const float* Wk   = (const float*)d_in[4];
  const float* bk   = (const float*)d_in[5];
  const float* Wv   = (const float*)d_in[6];
  const float* bv   = (const float*)d_in[7];
  const float* Wo   = (const float*)d_in[8];
  const float* bo   = (const float*)d_in[9];
  const float* W1   = (const float*)d_in[10];
  const float* b1   = (const float*)d_in[11];
  const float* W2   = (const float*)d_in[12];
  const float* b2   = (const float*)d_in[13];
  const float* ln1g = (const float*)d_in[14];
  const float* ln1b = (const float*)d_in[15];
  const float* ln2g = (const float*)d_in[16];
  const float* ln2b = (const float*)d_in[17];

  char* ws = (char*)d_ws;
  u16* WqkvT = (u16*)(ws + ((size_t)0 << 20));
  u16* WoT   = (u16*)(ws + ((size_t)6 << 20));
  u16* W1T   = (u16*)(ws + ((size_t)8 << 20));
  u16* W2T   = (u16*)(ws + ((size_t)16 << 20));
  u16* xb    = (u16*)(ws + ((size_t)24 << 20));
  u16* QKVb  = (u16*)(ws + ((size_t)32 << 20));
  u16* ctxb  = (u16*)(ws + ((size_t)56 << 20));
  float* x2f = (float*)(ws + ((size_t)48 << 20));
  u16* x2b   = xb;
  u16* VtG   = (u16*)(ws + ((size_t)64 << 20));
  float* pWo = (float*)(ws + ((size_t)64 << 20));  // 2 x 16MB partials
  u16* h1    = (u16*)(ws + ((size_t)64 << 20));    // 32MB
  float* pF2 = (float*)(ws + ((size_t)0 << 20));   // z0 at 0-16; z1 at 32-48

  dim3 blk(256);
  dim3 blk512(512);
  const int M = NBATCH * SEQ; // 4096

  // weight transposes (fp32 -> bf16, [K,N] -> [N,K])
  wtrans4_kernel<<<dim3(32, 32, 4), blk, 0, stream>>>(Wq, Wk, Wv, Wo, WqkvT, WoT);
  wtrans_kernel<<<dim3(128, 32), blk, 0, stream>>>(W1, W1T, EMB, FFDIM);
  wtrans_kernel<<<dim3(32, 128), blk, 0, stream>>>(W2, W2T, FFDIM, EMB);

  // LN1
  ln_kernel<<<M / 4, blk, 0, stream>>>(x, ln1g, ln1b, xb);

  // fused QKV projection: gemm_bt (768 blocks, ~4 resident/CU) + XCD swizzle
  gemm_bt<<<dim3(QKVLD / 128, M / 128), blk, 0, stream>>>(
      xb, WqkvT, bq, bk, bv, QKVb, nullptr, M, QKVLD, EMB, 3, 1.0f, EMB, nullptr, 0);

  // V^T per head
  vtrans_kernel<<<dim3(SEQ / 64, NBATCH * NHEAD), blk, 0, stream>>>(QKVb, VtG);

  // attention (paired q-tiles; double-buffered K/V staging)
  attn2_kernel<<<dim3(SEQ / 128, NBATCH * NHEAD), blk, 0, stream>>>(QKVb, VtG, ctxb);

  // output projection, gemm8 BM=128 split-K=2
  gemm8<128><<<dim3(EMB / 256, M / 128, 2), blk512, 0, stream>>>(
      ctxb, WoT, nullptr, nullptr, nullptr, nullptr, nullptr, M, EMB, EMB, 4, 1.0f,
      EMB / 2, pWo, (size_t)4 << 20);

  // LN2 fused with Wo reduce (+bo+x residual) -> x2f fp32 + x2b bf16
  ln2f_kernel<<<M / 4, blk, 0, stream>>>(pWo, (size_t)4 << 20, bo, x, ln2g, ln2b,
                                         x2b, x2f);

  // FFN1 + fast GELU: gemm8<256>
  gemm8<256><<<dim3(FFDIM / 256, M / 256), blk512, 0, stream>>>(
      x2b, W1T, b1, nullptr, nullptr, h1, nullptr, M, FFDIM, EMB, 1, 1.0f, EMB,
      nullptr, 0);

  // FFN2, gemm8 BM=128 split-K=2
  gemm8<128><<<dim3(EMB / 256, M / 128, 2), blk512, 0, stream>>>(
      h1, W2T, nullptr, nullptr, nullptr, nullptr, nullptr, M, EMB, FFDIM, 4, 1.0f,
      FFDIM / 2, pF2, (size_t)8 << 20);
  // d_out = p0 + p1 + b2 + x2f
  reduce2_kernel<<<M * EMB / 1024, blk, 0, stream>>>(pF2, (size_t)8 << 20, b2, x2f,
                                                     (float*)d_out, EMB);
}

// Round 7
// 407.871 us; speedup vs baseline: 1.0156x; 1.0156x over previous
//
#include <hip/hip_runtime.h>
#include <cmath>

typedef unsigned short u16;
typedef unsigned int u32;
typedef __bf16 bf16x8 __attribute__((ext_vector_type(8)));
typedef float f32x4 __attribute__((ext_vector_type(4)));

#define SEQ 2048
#define EMB 1024
#define NHEAD 16
#define HDIM 64
#define FFDIM 4096
#define NBATCH 2
#define QKVLD 3072  // fused QKV row stride
#define PWS 68      // attn Pw row stride (u16)

// Q pre-scale folds 1/sqrt(64) and 1/ln(2) so softmax uses exp2 directly.
#define QSCALE 0.18033688011112042f

__device__ __forceinline__ u16 f2bf(float f) {
  u32 u = __float_as_uint(f);
  u32 r = u + 0x7fffu + ((u >> 16) & 1u);
  return (u16)(r >> 16);
}

__device__ __forceinline__ float ex2(float x) {
#if __has_builtin(__builtin_amdgcn_exp2f)
  return __builtin_amdgcn_exp2f(x);
#else
  return exp2f(x);
#endif
}

// tanh-form GELU via a single exp2: gelu(x) = x * sigmoid(2u),
// u = 0.7978845608*(x + 0.044715 x^3).  max |err| vs exact erf ~3e-3.
__device__ __forceinline__ float geluf(float x) {
  float u = 0.7978845608028654f * (x + 0.044715f * x * x * x);
  float e = ex2(2.8853900817779268f * u);  // exp(2u)
  return x - x / (e + 1.0f);
}

// async global->LDS, 16B per lane. LDS dest must be wave-uniform base + lane*16.
__device__ __forceinline__ void gload16(const void* g, void* l) {
  __builtin_amdgcn_global_load_lds(
      (const __attribute__((address_space(1))) unsigned int*)g,
      (__attribute__((address_space(3))) unsigned int*)l, 16, 0, 0);
}

// 32-bit LDS byte address for inline-asm ds ops.
__device__ __forceinline__ u32 lds_addr(const void* p) {
  return (u32)(size_t)(const __attribute__((address_space(3))) void*)p;
}

// Inline-asm ds_read_b128: invisible to the compiler's waitcnt-insertion pass.
// Caller supplies ordering: counted vmcnt + barrier for RAW, and an explicit
// s_waitcnt lgkmcnt(0) + sched_barrier(0) before consuming (rule #18).
template <int IMM>
__device__ __forceinline__ bf16x8 dsr16(u32 a) {
  bf16x8 r;
  asm volatile("ds_read_b128 %0, %1 offset:%2" : "=v"(r) : "v"(a), "n"(IMM));
  return r;
}

// Row-chunk XCD swizzle (used by gemm_bt/QKV; measured-good there).
__device__ __forceinline__ void xcd_swizzle(int gx, int gy, int& bx, int& by) {
  int nwg = gx * gy;
  int lin = blockIdx.x + gx * blockIdx.y;
  int q = nwg >> 3;
  int nl = (lin & 7) * q + (lin >> 3);
  bx = nl % gx;
  by = nl / gx;
}

// 2-D TILED XCD swizzle (round-7): each XCD owns a TX x TY block-tile so its
// working set is TX B-panels + TY A-panels (row-chunking made every XCD touch
// ALL B-panels -> 2.2x FETCH on FFN1).  Requires gx%TX==0 and (nwg/8)%TX==0.
// XCDs arranged as (gx/TX) columns x (8/(gx/TX)) rows of tiles.
template <int TX>
__device__ __forceinline__ void xcd_tile_swizzle(int gx, int gy, int& bx, int& by) {
  int nwg = gx * gy;
  int lin = blockIdx.x + gx * blockIdx.y;
  int c = lin & 7;          // XCD id
  int wdx = lin >> 3;       // index within XCD chunk, 0..q-1
  int q = nwg >> 3;
  int TY = q / TX;
  int ncx = gx / TX;        // XCD tile columns
  int xt = c % ncx, yt = c / ncx;
  bx = xt * TX + wdx % TX;
  by = yt * TY + wdx / TX;
}

// ---------------- weight transposes + fp32->bf16 ----------------
// 4 square [1024x1024] weights in one dispatch: z=0..2 -> WqkvT rows, z=3 -> WoT
__global__ __launch_bounds__(256)
void wtrans4_kernel(const float* __restrict__ W0, const float* __restrict__ W1_,
                    const float* __restrict__ W2_, const float* __restrict__ W3,
                    u16* __restrict__ Dqkv, u16* __restrict__ Do) {
  __shared__ float tile[32][33];
  int z = blockIdx.z;
  const float* W = (z == 0) ? W0 : (z == 1) ? W1_ : (z == 2) ? W2_ : W3;
  u16* D = (z < 3) ? (Dqkv + (size_t)z * EMB * EMB) : Do;
  int tx = threadIdx.x & 31, ty = threadIdx.x >> 5;
  int n0 = blockIdx.x * 32, k0 = blockIdx.y * 32;
#pragma unroll
  for (int i = 0; i < 32; i += 8)
    tile[ty + i][tx] = W[(size_t)(k0 + ty + i) * EMB + (n0 + tx)];
  __syncthreads();
#pragma unroll
  for (int i = 0; i < 32; i += 8)
    D[(size_t)(n0 + ty + i) * EMB + (k0 + tx)] = f2bf(tile[tx][ty + i]);
}

// W1 [1024,4096] -> W1T [4096,1024] and W2 [4096,1024] -> W2T [1024,4096]
// in ONE dispatch (z selects; 4096 blocks each, lin remapped per shape).
__global__ __launch_bounds__(256)
void wtrans2_kernel(const float* __restrict__ W1_, const float* __restrict__ W2_,
                    u16* __restrict__ W1T, u16* __restrict__ W2T) {
  __shared__ float tile[32][33];
  int z = blockIdx.z;
  const float* W = z ? W2_ : W1_;
  u16* WT = z ? W2T : W1T;
  int K = z ? FFDIM : EMB;   // rows of W
  int N = z ? EMB : FFDIM;   // cols of W
  int lin = blockIdx.x + 128 * blockIdx.y;
  int nb = N >> 5;
  int n0 = (lin % nb) * 32, k0 = (lin / nb) * 32;
  int tx = threadIdx.x & 31, ty = threadIdx.x >> 5;
#pragma unroll
  for (int i = 0; i < 32; i += 8)
    tile[ty + i][tx] = W[(size_t)(k0 + ty + i) * N + (n0 + tx)];
  __syncthreads();
#pragma unroll
  for (int i = 0; i < 32; i += 8)
    WT[(size_t)(n0 + ty + i) * K + (k0 + tx)] = f2bf(tile[tx][ty + i]);
}

// ---------------- V transpose per head: QKV [B*S,3072] (V at col 2048+h*64)
// -> Vt [B*H, 64, SEQ]
__global__ __launch_bounds__(256)
void vtrans_kernel(const u16* __restrict__ QKV, u16* __restrict__ Vt) {
  __shared__ u16 tile[64 * 72];
  int bh = blockIdx.y, b = bh >> 4, h = bh & 15;
  int s0 = blockIdx.x * 64;
  const u16* src = QKV + (size_t)b * SEQ * QKVLD + 2048 + (size_t)h * HDIM;
  int tid = threadIdx.x;
#pragma unroll
  for (int cc = 0; cc < 2; ++cc) {
    int c = tid + cc * 256;
    int s = c >> 3, d0 = (c & 7) * 8;
    uint4 v = *(const uint4*)(src + (size_t)(s0 + s) * QKVLD + d0);
    *(uint4*)(&tile[s * 72 + d0]) = v;
  }
  __syncthreads();
  u16* dst = Vt + (size_t)bh * HDIM * SEQ;
#pragma unroll
  for (int cc = 0; cc < 2; ++cc) {
    int c = tid + cc * 256;
    int d = c >> 3, t0l = (c & 7) * 8;
    union { uint4 u; u16 s[8]; } ou;
#pragma unroll
    for (int j = 0; j < 8; ++j) ou.s[j] = tile[(t0l + j) * 72 + d];
    *(uint4*)(dst + (size_t)d * SEQ + s0 + t0l) = ou.u;
  }
}

// ---------------- layernorm: 1 row per wave, 4 rows per block ----------------
__global__ __launch_bounds__(256)
void ln_kernel(const float* __restrict__ in, const float* __restrict__ gamma,
               const float* __restrict__ beta, u16* __restrict__ outb) {
  int w = threadIdx.x >> 6, lane = threadIdx.x & 63;
  int row = blockIdx.x * 4 + w;
  size_t base = (size_t)row * EMB;
  float4 v[4];
  float s = 0.f, q = 0.f;
#pragma unroll
  for (int j = 0; j < 4; ++j) {
    v[j] = *(const float4*)(in + base + j * 256 + lane * 4);
    s += v[j].x + v[j].y + v[j].z + v[j].w;
    q += v[j].x * v[j].x + v[j].y * v[j].y + v[j].z * v[j].z + v[j].w * v[j].w;
  }
#pragma unroll
  for (int off = 1; off < 64; off <<= 1) {
    s += __shfl_xor(s, off);
    q += __shfl_xor(q, off);
  }
  float mean = s * (1.0f / EMB);
  float var = q * (1.0f / EMB) - mean * mean;
  float rstd = rsqrtf(var + 1e-5f);
#pragma unroll
  for (int j = 0; j < 4; ++j) {
    int c = j * 256 + lane * 4;
    float4 g4 = *(const float4*)(gamma + c);
    float4 b4 = *(const float4*)(beta + c);
    ushort4 ob;
    ob.x = f2bf((v[j].x - mean) * rstd * g4.x + b4.x);
    ob.y = f2bf((v[j].y - mean) * rstd * g4.y + b4.y);
    ob.z = f2bf((v[j].z - mean) * rstd * g4.z + b4.z);
    ob.w = f2bf((v[j].w - mean) * rstd * g4.w + b4.w);
    *(ushort4*)(outb + base + c) = ob;
  }
}

// ---------------- LN2 fused with Wo split-K reduce ----------------
// in = p[0]+p[pstride]+bias(col)+resid; layernorm(in) -> bf16 + fp32
__global__ __launch_bounds__(256)
void ln2f_kernel(const float* __restrict__ p, size_t pstride,
                 const float* __restrict__ bias, const float* __restrict__ resid,
                 const float* __restrict__ gamma, const float* __restrict__ beta,
                 u16* __restrict__ outb, float* __restrict__ outf) {
  int w = threadIdx.x >> 6, lane = threadIdx.x & 63;
  int row = blockIdx.x * 4 + w;
  size_t base = (size_t)row * EMB;
  float4 v[4];
  float s = 0.f, q = 0.f;
#pragma unroll
  for (int j = 0; j < 4; ++j) {
    int c = j * 256 + lane * 4;
    float4 a = *(const float4*)(p + base + c);
    float4 b = *(const float4*)(p + pstride + base + c);
    float4 r = *(const float4*)(resid + base + c);
    float4 bb = *(const float4*)(bias + c);
    v[j].x = a.x + b.x + r.x + bb.x;
    v[j].y = a.y + b.y + r.y + bb.y;
    v[j].z = a.z + b.z + r.z + bb.z;
    v[j].w = a.w + b.w + r.w + bb.w;
    s += v[j].x + v[j].y + v[j].z + v[j].w;
    q += v[j].x * v[j].x + v[j].y * v[j].y + v[j].z * v[j].z + v[j].w * v[j].w;
  }
#pragma unroll
  for (int off = 1; off < 64; off <<= 1) {
    s += __shfl_xor(s, off);
    q += __shfl_xor(q, off);
  }
  float mean = s * (1.0f / EMB);
  float var = q * (1.0f / EMB) - mean * mean;
  float rstd = rsqrtf(var + 1e-5f);
#pragma unroll
  for (int j = 0; j < 4; ++j) {
    int c = j * 256 + lane * 4;
    float4 g4 = *(const float4*)(gamma + c);
    float4 b4 = *(const float4*)(beta + c);
    float y0 = (v[j].x - mean) * rstd * g4.x + b4.x;
    float y1 = (v[j].y - mean) * rstd * g4.y + b4.y;
    float y2 = (v[j].z - mean) * rstd * g4.z + b4.z;
    float y3 = (v[j].w - mean) * rstd * g4.w + b4.w;
    ushort4 ob;
    ob.x = f2bf(y0); ob.y = f2bf(y1); ob.z = f2bf(y2); ob.w = f2bf(y3);
    *(ushort4*)(outb + base + c) = ob;
    *(float4*)(outf + base + c) = make_float4(y0, y1, y2, y3);
  }
}

// ---------------- split-K reduce: out = p[z0]+p[z1]+bias+resid (fp32) --------
__global__ __launch_bounds__(256)
void reduce2_kernel(const float* __restrict__ p, size_t pstride,
                    const float* __restrict__ bias, const float* __restrict__ resid,
                    float* __restrict__ out, int ncols) {
  size_t i = ((size_t)blockIdx.x * 256 + threadIdx.x) * 4;
  float4 a = *(const float4*)(p + i);
  float4 b = *(const float4*)(p + pstride + i);
  float4 r = *(const float4*)(resid + i);
  int col = (int)(i & (size_t)(ncols - 1));
  float4 bb = *(const float4*)(bias + col);
  float4 o;
  o.x = a.x + b.x + r.x + bb.x;
  o.y = a.y + b.y + r.y + bb.y;
  o.z = a.z + b.z + r.z + bb.z;
  o.w = a.w + b.w + r.w + bb.w;
  *(float4*)(out + i) = o;
}

// ---------------- GEMM (round-0 structure): C[M,N] = A*BT^T, 128x128 tile ----
// 256 threads, 32KB LDS -> 4 resident blocks/CU; per-K-step full drain is
// hidden by cross-block overlap (m114 mechanism).  + row-chunk XCD swizzle.
__global__ __launch_bounds__(256)
void gemm_bt(const u16* __restrict__ A, const u16* __restrict__ BT,
             const float* __restrict__ bias, const float* __restrict__ bias2,
             const float* __restrict__ bias3, void* __restrict__ out,
             const float* __restrict__ resid, int M, int N, int K,
             int mode, float scale, int ksplit,
             float* __restrict__ partial, size_t pstride) {
  __shared__ __align__(16) u16 As[128 * 64];
  __shared__ __align__(16) u16 Bs[128 * 64];
  int tid = threadIdx.x;
  int lane = tid & 63, w = tid >> 6;
  int wm = w >> 1, wn = w & 1;
  int g = lane >> 4, lr = lane & 15;
  int bx, by;
  xcd_swizzle(gridDim.x, gridDim.y, bx, by);
  int m0 = by * 128, n0 = bx * 128;
  int z = blockIdx.z;
  int kbeg = z * ksplit, kend = kbeg + ksplit;

  f32x4 acc[4][4];
#pragma unroll
  for (int mt = 0; mt < 4; ++mt)
#pragma unroll
    for (int nt = 0; nt < 4; ++nt) {
      acc[mt][nt][0] = 0.f; acc[mt][nt][1] = 0.f;
      acc[mt][nt][2] = 0.f; acc[mt][nt][3] = 0.f;
    }

  size_t ao[4], bo_[4];
  int lo[4];
#pragma unroll
  for (int cc = 0; cc < 4; ++cc) {
    int c = tid + cc * 256;
    int row = c >> 3, slot = c & 7;
    int gc = slot ^ (row & 7);
    ao[cc] = (size_t)(m0 + row) * K + gc * 8;
    bo_[cc] = (size_t)(n0 + row) * K + gc * 8;
    lo[cc] = c * 8;
  }
  int swz[2];
#pragma unroll
  for (int kk = 0; kk < 2; ++kk) swz[kk] = ((kk * 4 + g) ^ (lr & 7)) * 8;

  for (int k0 = kbeg; k0 < kend; k0 += 64) {
    __syncthreads();
#pragma unroll
    for (int cc = 0; cc < 4; ++cc) gload16(A + ao[cc] + k0, As + lo[cc]);
#pragma unroll
    for (int cc = 0; cc < 4; ++cc) gload16(BT + bo_[cc] + k0, Bs + lo[cc]);
    __syncthreads();
#pragma unroll
    for (int kk = 0; kk < 2; ++kk) {
      bf16x8 af[4], bfr[4];
#pragma unroll
      for (int mt = 0; mt < 4; ++mt)
        af[mt] = *(const bf16x8*)(As + (wm * 64 + mt * 16 + lr) * 64 + swz[kk]);
#pragma unroll
      for (int nt = 0; nt < 4; ++nt)
        bfr[nt] = *(const bf16x8*)(Bs + (wn * 64 + nt * 16 + lr) * 64 + swz[kk]);
#pragma unroll
      for (int mt = 0; mt < 4; ++mt)
#pragma unroll
        for (int nt = 0; nt < 4; ++nt)
          acc[mt][nt] = __builtin_amdgcn_mfma_f32_16x16x32_bf16(af[mt], bfr[nt], acc[mt][nt], 0, 0, 0);
    }
  }

  float* pz = partial + (size_t)z * pstride;
#pragma unroll
  for (int mt = 0; mt < 4; ++mt) {
    int row = m0 + wm * 64 + mt * 16 + g * 4;
#pragma unroll
    for (int nt = 0; nt < 4; ++nt) {
      int col = n0 + wn * 64 + nt * 16 + lr;
      float bcol;
      if (mode == 3) {
        int which = col >> 10;
        const float* bp = (which == 0) ? bias : (which == 1) ? bias2 : bias3;
        bcol = bp[col & 1023];
      } else if (mode != 4) {
        bcol = bias[col];
      } else {
        bcol = 0.f;
      }
#pragma unroll
      for (int r = 0; r < 4; ++r) {
        float vacc = acc[mt][nt][r] + bcol;
        size_t idx = (size_t)(row + r) * N + col;
        if (mode == 0)      ((u16*)out)[idx] = f2bf(vacc * scale);
        else if (mode == 1) ((u16*)out)[idx] = f2bf(geluf(vacc));
        else if (mode == 2) ((float*)out)[idx] = vacc + resid[idx];
        else if (mode == 3) ((u16*)out)[idx] = f2bf(col < 1024 ? vacc * QSCALE : vacc);
        else                pz[idx] = vacc;
      }
    }
  }
}

// ====================================================================
// gemm8<BM,TXS>: BMx256 tile, BK=64, 512 threads (8 waves, 2M x 4N),
// 8-phase / 2-K-tile pipelined K-loop with counted vmcnt, asm ds_reads,
// 2-D tiled XCD swizzle (TXS = XCD tile width in blocks).
// ====================================================================

#define BARM __builtin_amdgcn_s_barrier()
#define VMWS asm volatile("s_waitcnt vmcnt(%0)" ::"n"(4 + RA))
#define VMW0 asm volatile("s_waitcnt vmcnt(0)")
#define NOSTG ((void)0)
#define NOWT ((void)0)

#define STG_A(t, d, kh)                                                       \
  { _Pragma("unroll")                                                         \
    for (int j = 0; j < RA; ++j)                                              \
      gload16(A + (size_t)sgA[j] + kbeg + (t) * 64 + (kh) * 32,               \
              As + ((d) * 2 + (kh)) * ABUF + slA[j]); }

#define STG_B(t, d, kh)                                                       \
  { _Pragma("unroll")                                                         \
    for (int j = 0; j < 2; ++j)                                               \
      gload16(BT + (size_t)sgB[j] + kbeg + (t) * 64 + (kh) * 32,              \
              Bs + ((d) * 2 + (kh)) * 8192 + slB[j]); }

#define PHASE(d, kk, mh, STAGE, WAITC)                                        \
  {                                                                           \
    const u32 bA = bB + ((d) * 2 + (kk)) * 16384;                             \
    const u32 aA = aB + ((d) * 2 + (kk)) * (ABUF * 2);                        \
    if ((mh) == 0) {                                                          \
      bfr[0] = dsr16<0>(bA);                                                  \
      bfr[1] = dsr16<1024>(bA);                                               \
      bfr[2] = dsr16<2048>(bA);                                               \
      bfr[3] = dsr16<3072>(bA);                                               \
    }                                                                         \
    bf16x8 af[MT2];                                                           \
    af[0] = dsr16<(((mh) * MT2 + 0) * 1024)>(aA);                             \
    af[1] = dsr16<(((mh) * MT2 + 1) * 1024)>(aA);                             \
    if constexpr (MT2 > 2) {                                                  \
      af[2] = dsr16<(((mh) * MT2 + 2) * 1024)>(aA);                           \
      af[3] = dsr16<(((mh) * MT2 + 3) * 1024)>(aA);                           \
    }                                                                         \
    STAGE;                                                                    \
    BARM;                                                                     \
    asm volatile("s_waitcnt lgkmcnt(0)");                                     \
    __builtin_amdgcn_sched_barrier(0);                                        \
    __builtin_amdgcn_s_setprio(1);                                            \
    _Pragma("unroll")                                                         \
    for (int mi = 0; mi < MT2; ++mi)                                          \
      _Pragma("unroll")                                                       \
      for (int nt = 0; nt < 4; ++nt)                                          \
        acc[(mh) * MT2 + mi][nt] = __builtin_amdgcn_mfma_f32_16x16x32_bf16(   \
            af[mi], bfr[nt], acc[(mh) * MT2 + mi][nt], 0, 0, 0);              \
    __builtin_amdgcn_s_setprio(0);                                            \
    WAITC;                                                                    \
    BARM;                                                                     \
  }

// shared epilogue
#define GEMM_EPILOGUE                                                         \
  float* pz = partial + (size_t)z * pstride;                                  \
  _Pragma("unroll")                                                           \
  for (int mt = 0; mt < MT; ++mt) {                                           \
    int row = m0 + wm * (BM / 2) + mt * 16 + g * 4;                           \
    _Pragma("unroll")                                                         \
    for (int nt = 0; nt < 4; ++nt) {                                          \
      int col = n0 + wn * 64 + nt * 16 + lr;                                  \
      float bcol;                                                             \
      if (mode == 3) {                                                        \
        int which = col >> 10;                                                \
        const float* bp = (which == 0) ? bias : (which == 1) ? bias2 : bias3; \
        bcol = bp[col & 1023];                                                \
      } else if (mode != 4) {                                                 \
        bcol = bias[col];                                                     \
      } else {                                                                \
        bcol = 0.f;                                                           \
      }                                                                       \
      _Pragma("unroll")                                                       \
      for (int r = 0; r < 4; ++r) {                                           \
        float vacc = acc[mt][nt][r] + bcol;                                   \
        size_t idx = (size_t)(row + r) * N + col;                             \
        if (mode == 0)      ((u16*)out)[idx] = f2bf(vacc * scale);            \
        else if (mode == 1) ((u16*)out)[idx] = f2bf(geluf(vacc));             \
        else if (mode == 2) ((float*)out)[idx] = vacc + resid[idx];           \
        else if (mode == 3) ((u16*)out)[idx] = f2bf(col < 1024 ? vacc * QSCALE : vacc); \
        else                pz[idx] = vacc;                                   \
      }                                                                       \
    }                                                                         \
  }

#define GEMM_PRELUDE                                                          \
  constexpr int MT = BM / 32;                                                 \
  constexpr int MT2 = MT / 2;                                                 \
  constexpr int RA = BM / 128;                                                \
  constexpr int ABUF = BM * 32;                                               \
  __shared__ __align__(16) u16 As[4 * ABUF];                                  \
  __shared__ __align__(16) u16 Bs[4 * 8192];                                  \
  int tid = threadIdx.x;                                                      \
  int lane = tid & 63, w = tid >> 6;                                          \
  int wm = w >> 2, wn = w & 3;                                                \
  int g = lane >> 4, lr = lane & 15;                                          \
  int bx, by;                                                                 \
  xcd_tile_swizzle<TXS>(gridDim.x, gridDim.y, bx, by);                        \
  int m0 = by * BM, n0 = bx * 256;                                            \
  int z = blockIdx.z;                                                         \
  size_t kbeg = (size_t)z * ksplit;                                           \
  int nk = ksplit >> 6;                                                       \
  int phys = ((lr & 1) * 4 + g) ^ ((lr >> 1) & 7);                            \
  int aoff = wm * (BM / 2) * 32 + (lr >> 1) * 64 + phys * 8;                  \
  int boff = wn * 2048 + (lr >> 1) * 64 + phys * 8;                           \
  const u32 aB = lds_addr(As) + 2 * aoff;                                     \
  const u32 bB = lds_addr(Bs) + 2 * boff;                                     \
  int sgA[RA], slA[RA];                                                       \
  _Pragma("unroll")                                                           \
  for (int j = 0; j < RA; ++j) {                                              \
    int c = tid + j * 512;                                                    \
    int sr = c >> 3, ph = c & 7, l = ph ^ (sr & 7);                           \
    sgA[j] = (m0 + 2 * sr + (l >> 2)) * K + (l & 3) * 8;                      \
    slA[j] = c * 8;                                                           \
  }                                                                           \
  int sgB[2], slB[2];                                                         \
  _Pragma("unroll")                                                           \
  for (int j = 0; j < 2; ++j) {                                               \
    int c = tid + j * 512;                                                    \
    int sr = c >> 3, ph = c & 7, l = ph ^ (sr & 7);                           \
    sgB[j] = (n0 + 2 * sr + (l >> 2)) * K + (l & 3) * 8;                      \
    slB[j] = c * 8;                                                           \
  }                                                                           \
  f32x4 acc[MT][4];                                                           \
  _Pragma("unroll")                                                           \
  for (int mt = 0; mt < MT; ++mt)                                             \
    _Pragma("unroll")                                                         \
    for (int nt = 0; nt < 4; ++nt) {                                          \
      acc[mt][nt][0] = 0.f; acc[mt][nt][1] = 0.f;                             \
      acc[mt][nt][2] = 0.f; acc[mt][nt][3] = 0.f;                             \
    }                                                                         \
  bf16x8 bfr[4];

// gemm8<BM,TXS>: 8-phase ring
template <int BM, int TXS>
__global__ __launch_bounds__(512, 2)
void gemm8(const u16* __restrict__ A, const u16* __restrict__ BT,
           const float* __restrict__ bias, const float* __restrict__ bias2,
           const float* __restrict__ bias3, void* __restrict__ out,
           const float* __restrict__ resid, int M, int N, int K,
           int mode, float scale, int ksplit,
           float* __restrict__ partial, size_t pstride) {
  GEMM_PRELUDE
  int npair = nk >> 1;

  STG_B(0, 0, 0); STG_A(0, 0, 0); STG_B(0, 0, 1); STG_A(0, 0, 1);
  STG_B(1, 1, 0); STG_A(1, 1, 0); STG_B(1, 1, 1);
  VMWS; BARM;

  for (int it = 0; it < npair - 1; ++it) {
    int t1 = 2 * it + 1, t2 = 2 * it + 2, t3 = 2 * it + 3;
    PHASE(0, 0, 0, STG_A(t1, 1, 1), NOWT)
    PHASE(0, 0, 1, STG_B(t2, 0, 0), NOWT)
    PHASE(0, 1, 0, STG_A(t2, 0, 0), NOWT)
    PHASE(0, 1, 1, STG_B(t2, 0, 1), VMWS)
    PHASE(1, 0, 0, STG_A(t2, 0, 1), NOWT)
    PHASE(1, 0, 1, STG_B(t3, 1, 0), NOWT)
    PHASE(1, 1, 0, STG_A(t3, 1, 0), NOWT)
    PHASE(1, 1, 1, STG_B(t3, 1, 1), VMWS)
  }
  {
    int t1 = nk - 1;
    PHASE(0, 0, 0, STG_A(t1, 1, 1), NOWT)
    PHASE(0, 0, 1, NOSTG, NOWT)
    PHASE(0, 1, 0, NOSTG, NOWT)
    PHASE(0, 1, 1, NOSTG, VMW0)
    PHASE(1, 0, 0, NOSTG, NOWT)
    PHASE(1, 0, 1, NOSTG, NOWT)
    PHASE(1, 1, 0, NOSTG, NOWT)
    PHASE(1, 1, 1, NOSTG, NOWT)
  }
  GEMM_EPILOGUE
}

// ---------------- flash attention, paired q-tiles, no-max exp2 softmax -------
// (round-5 known-good structure; round-6 double-buffer reverted: the plain LDS
// reads alias in-flight global_load_lds -> compiler drains the prefetch too.)
__shared__ __align__(16) u16 attn_Kt[64 * 64];
__shared__ __align__(16) u16 attn_VT[64 * 64];
__shared__ __align__(16) u16 attn_Pw[2][4][16 * PWS];

template <int S0>
__device__ __forceinline__ void attn_tile(
    int t0, const int* q0, int w, int g, int lr, const bf16x8& ones,
    bf16x8 (&qf)[2][2], f32x4 (&lacc)[2], f32x4 (&oacc)[2][4]) {
  f32x4 sacc[2][4];
#pragma unroll
  for (int s = S0; s < 2; ++s)
#pragma unroll
    for (int nt = 0; nt < 4; ++nt) {
      sacc[s][nt][0] = 0.f; sacc[s][nt][1] = 0.f;
      sacc[s][nt][2] = 0.f; sacc[s][nt][3] = 0.f;
    }
#pragma unroll
  for (int kk = 0; kk < 2; ++kk)
#pragma unroll
    for (int nt = 0; nt < 4; ++nt) {
      int sw = ((kk * 4 + g) ^ lr) & 7;
      bf16x8 bfr = *(const bf16x8*)(&attn_Kt[(nt * 16 + lr) * 64 + sw * 8]);
      if (S0 == 0)
        sacc[0][nt] = __builtin_amdgcn_mfma_f32_16x16x32_bf16(qf[0][kk], bfr, sacc[0][nt], 0, 0, 0);
      sacc[1][nt] = __builtin_amdgcn_mfma_f32_16x16x32_bf16(qf[1][kk], bfr, sacc[1][nt], 0, 0, 0);
    }

#pragma unroll
  for (int s = S0; s < 2; ++s) {
    bool diag = (t0 == q0[s]);  // wave-uniform
#pragma unroll
    for (int r = 0; r < 4; ++r) {
#pragma unroll
      for (int nt = 0; nt < 4; ++nt) {
        float pv = ex2(sacc[s][nt][r]);
        if (diag && (nt * 16 + lr > w * 16 + g * 4 + r)) pv = 0.f;
        attn_Pw[s][w][(g * 4 + r) * PWS + nt * 16 + lr] = f2bf(pv);
      }
    }
  }

#pragma unroll
  for (int kk = 0; kk < 2; ++kk) {
    bf16x8 pf0, pf1;
    if (S0 == 0) pf0 = *(const bf16x8*)(&attn_Pw[0][w][lr * PWS + kk * 32 + g * 8]);
    pf1 = *(const bf16x8*)(&attn_Pw[1][w][lr * PWS + kk * 32 + g * 8]);
#pragma unroll
    for (int nt = 0; nt < 4; ++nt) {
      int sw = ((kk * 4 + g) ^ lr) & 7;
      bf16x8 vf = *(const bf16x8*)(&attn_VT[(nt * 16 + lr) * 64 + sw * 8]);
      if (S0 == 0)
        oacc[0][nt] = __builtin_amdgcn_mfma_f32_16x16x32_bf16(pf0, vf, oacc[0][nt], 0, 0, 0);
      oacc[1][nt] = __builtin_amdgcn_mfma_f32_16x16x32_bf16(pf1, vf, oacc[1][nt], 0, 0, 0);
    }
    if (S0 == 0)
      lacc[0] = __builtin_amdgcn_mfma_f32_16x16x32_bf16(pf0, ones, lacc[0], 0, 0, 0);
    lacc[1] = __builtin_amdgcn_mfma_f32_16x16x32_bf16(pf1, ones, lacc[1], 0, 0, 0);
  }
}

__global__ __launch_bounds__(256)
void attn2_kernel(const u16* __restrict__ QKV, const u16* __restrict__ Vt,
                  u16* __restrict__ ctx) {
  int tid = threadIdx.x, lane = tid & 63, w = tid >> 6;
  int g = lane >> 4, lr = lane & 15;
  int bh = blockIdx.y, b = bh >> 4, h = bh & 15;
  int q0[2];
  q0[0] = blockIdx.x * 64;
  q0[1] = (SEQ / 64 - 1 - blockIdx.x) * 64;
  const u16* Qh = QKV + (size_t)b * SEQ * QKVLD + (size_t)h * HDIM;
  const u16* Kh = Qh + 1024;
  const u16* Vth = Vt + (size_t)bh * HDIM * SEQ;

  bf16x8 ones;
#pragma unroll
  for (int j = 0; j < 8; ++j) ones[j] = (__bf16)1.0f;

  bf16x8 qf[2][2];
#pragma unroll
  for (int s = 0; s < 2; ++s)
#pragma unroll
    for (int kk = 0; kk < 2; ++kk)
      qf[s][kk] = *(const bf16x8*)(Qh + (size_t)(q0[s] + w * 16 + lr) * QKVLD + kk * 32 + g * 8);

  f32x4 lacc[2];
  f32x4 oacc[2][4];
#pragma unroll
  for (int s = 0; s < 2; ++s) {
    lacc[s][0] = 0.f; lacc[s][1] = 0.f; lacc[s][2] = 0.f; lacc[s][3] = 0.f;
#pragma unroll
    for (int nt = 0; nt < 4; ++nt) {
      oacc[s][nt][0] = 0.f; oacc[s][nt][1] = 0.f;
      oacc[s][nt][2] = 0.f; oacc[s][nt][3] = 0.f;
    }
  }

  int c1 = tid, c2 = tid + 256;
  int t1 = c1 >> 3, ch1 = (c1 ^ t1) & 7;
  int t2 = c2 >> 3, ch2 = (c2 ^ t2) & 7;
  for (int t0 = 0; t0 <= q0[1]; t0 += 64) {
    __syncthreads();
    gload16(Kh + (size_t)(t0 + t1) * QKVLD + ch1 * 8, attn_Kt + c1 * 8);
    gload16(Kh + (size_t)(t0 + t2) * QKVLD + ch2 * 8, attn_Kt + c2 * 8);
    gload16(Vth + (size_t)t1 * SEQ + t0 + ch1 * 8, attn_VT + c1 * 8);
    gload16(Vth + (size_t)t2 * SEQ + t0 + ch2 * 8, attn_VT + c2 * 8);
    __syncthreads();

    if (t0 <= q0[0])
      attn_tile<0>(t0, q0, w, g, lr, ones, qf, lacc, oacc);
    else
      attn_tile<1>(t0, q0, w, g, lr, ones, qf, lacc, oacc);
  }

#pragma unroll
  for (int s = 0; s < 2; ++s) {
    int srow = q0[s] + w * 16 + g * 4;
    float inv[4];
#pragma unroll
    for (int r = 0; r < 4; ++r) inv[r] = 1.0f / lacc[s][r];
#pragma unroll
    for (int nt = 0; nt < 4; ++nt) {
      int col = h * HDIM + nt * 16 + lr;
#pragma unroll
      for (int r = 0; r < 4; ++r) {
        float o = oacc[s][nt][r] * inv[r];
        ctx[((size_t)b * SEQ + srow + r) * EMB + col] = f2bf(o);
      }
    }
  }
}

// ---------------- launch ----------------
extern "C" void kernel_launch(void* const* d_in, const int* in_sizes, int n_in,
                              void* d_out, int out_size, void* d_ws, size_t ws_size,
                              hipStream_t stream) {
  const float* x    = (const float*)d_in[0];
  const float* Wq   = (const float*)d_in[2];
  const float* bq   = (const float*)d_in[3];
  const float* Wk   = (const float*)d_in[4];
  const float* bk   = (const float*)d_in[5];
  const float* Wv   = (const float*)d_in[6];
  const float* bv   = (const float*)d_in[7];
  const float* Wo   = (const float*)d_in[8];
  const float* bo   = (const float*)d_in[9];
  const float* W1   = (const float*)d_in[10];
  const float* b1   = (const float*)d_in[11];
  const float* W2   = (const float*)d_in[12];
  const float* b2   = (const float*)d_in[13];
  const float* ln1g = (const float*)d_in[14];
  const float* ln1b = (const float*)d_in[15];
  const float* ln2g = (const float*)d_in[16];
  const float* ln2b = (const float*)d_in[17];

  char* ws = (char*)d_ws;
  u16* WqkvT = (u16*)(ws + ((size_t)0 << 20));
  u16* WoT   = (u16*)(ws + ((size_t)6 << 20));
  u16* W1T   = (u16*)(ws + ((size_t)8 << 20));
  u16* W2T   = (u16*)(ws + ((size_t)16 << 20));
  u16* xb    = (u16*)(ws + ((size_t)24 << 20));
  u16* QKVb  = (u16*)(ws + ((size_t)32 << 20));
  u16* ctxb  = (u16*)(ws + ((size_t)56 << 20));
  float* x2f = (float*)(ws + ((size_t)48 << 20));
  u16* x2b   = xb;
  u16* VtG   = (u16*)(ws + ((size_t)64 << 20));
  float* pWo = (float*)(ws + ((size_t)64 << 20));  // 2 x 16MB partials
  u16* h1    = (u16*)(ws + ((size_t)64 << 20));    // 32MB
  float* pF2 = (float*)(ws + ((size_t)0 << 20));   // z0 at 0-16; z1 at 32-48

  dim3 blk(256);
  dim3 blk512(512);
  const int M = NBATCH * SEQ; // 4096

  // weight transposes (fp32 -> bf16, [K,N] -> [N,K]); W1+W2 merged in one dispatch
  wtrans4_kernel<<<dim3(32, 32, 4), blk, 0, stream>>>(Wq, Wk, Wv, Wo, WqkvT, WoT);
  wtrans2_kernel<<<dim3(128, 32, 2), blk, 0, stream>>>(W1, W2, W1T, W2T);

  // LN1
  ln_kernel<<<M / 4, blk, 0, stream>>>(x, ln1g, ln1b, xb);

  // fused QKV projection: gemm_bt (768 blocks, ~4 resident/CU) + XCD swizzle
  gemm_bt<<<dim3(QKVLD / 128, M / 128), blk, 0, stream>>>(
      xb, WqkvT, bq, bk, bv, QKVb, nullptr, M, QKVLD, EMB, 3, 1.0f, EMB, nullptr, 0);

  // V^T per head
  vtrans_kernel<<<dim3(SEQ / 64, NBATCH * NHEAD), blk, 0, stream>>>(QKVb, VtG);

  // attention (paired q-tiles: uniform 33 iterations/block)
  attn2_kernel<<<dim3(SEQ / 128, NBATCH * NHEAD), blk, 0, stream>>>(QKVb, VtG, ctxb);

  // output projection, gemm8 BM=128 split-K=2, 4x4 XCD tiles
  gemm8<128, 4><<<dim3(EMB / 256, M / 128, 2), blk512, 0, stream>>>(
      ctxb, WoT, nullptr, nullptr, nullptr, nullptr, nullptr, M, EMB, EMB, 4, 1.0f,
      EMB / 2, pWo, (size_t)4 << 20);

  // LN2 fused with Wo reduce (+bo+x residual) -> x2f fp32 + x2b bf16
  ln2f_kernel<<<M / 4, blk, 0, stream>>>(pWo, (size_t)4 << 20, bo, x, ln2g, ln2b,
                                         x2b, x2f);

  // FFN1 + fast GELU: gemm8<256>, 8x4 XCD tiles (16x16 grid)
  gemm8<256, 8><<<dim3(FFDIM / 256, M / 256), blk512, 0, stream>>>(
      x2b, W1T, b1, nullptr, nullptr, h1, nullptr, M, FFDIM, EMB, 1, 1.0f, EMB,
      nullptr, 0);

  // FFN2, gemm8 BM=128 split-K=2, 4x4 XCD tiles
  gemm8<128, 4><<<dim3(EMB / 256, M / 128, 2), blk512, 0, stream>>>(
      h1, W2T, nullptr, nullptr, nullptr, nullptr, nullptr, M, EMB, FFDIM, 4, 1.0f,
      FFDIM / 2, pF2, (size_t)8 << 20);
  // d_out = p0 + p1 + b2 + x2f
  reduce2_kernel<<<M * EMB / 1024, blk, 0, stream>>>(pF2, (size_t)8 << 20, b2, x2f,
                                                     (float*)d_out, EMB);
}

// Round 8
// 404.904 us; speedup vs baseline: 1.0230x; 1.0073x over previous
//
#include <hip/hip_runtime.h>
#include <cmath>

typedef unsigned short u16;
typedef unsigned int u32;
typedef __bf16 bf16x8 __attribute__((ext_vector_type(8)));
typedef float f32x4 __attribute__((ext_vector_type(4)));

#define SEQ 2048
#define EMB 1024
#define NHEAD 16
#define HDIM 64
#define FFDIM 4096
#define NBATCH 2
#define QKVLD 3072  // fused QKV row stride
#define PWS 68      // attn Pw row stride (u16)

// Q pre-scale folds 1/sqrt(64) and 1/ln(2) so softmax uses exp2 directly.
#define QSCALE 0.18033688011112042f

__device__ __forceinline__ u16 f2bf(float f) {
  u32 u = __float_as_uint(f);
  u32 r = u + 0x7fffu + ((u >> 16) & 1u);
  return (u16)(r >> 16);
}

__device__ __forceinline__ float ex2(float x) {
#if __has_builtin(__builtin_amdgcn_exp2f)
  return __builtin_amdgcn_exp2f(x);
#else
  return exp2f(x);
#endif
}

// tanh-form GELU via a single exp2: gelu(x) = x * sigmoid(2u),
// u = 0.7978845608*(x + 0.044715 x^3).  max |err| vs exact erf ~3e-3.
__device__ __forceinline__ float geluf(float x) {
  float u = 0.7978845608028654f * (x + 0.044715f * x * x * x);
  float e = ex2(2.8853900817779268f * u);  // exp(2u)
  return x - x / (e + 1.0f);
}

// async global->LDS, 16B per lane. LDS dest must be wave-uniform base + lane*16.
__device__ __forceinline__ void gload16(const void* g, void* l) {
  __builtin_amdgcn_global_load_lds(
      (const __attribute__((address_space(1))) unsigned int*)g,
      (__attribute__((address_space(3))) unsigned int*)l, 16, 0, 0);
}

// 32-bit LDS byte address for inline-asm ds ops.
__device__ __forceinline__ u32 lds_addr(const void* p) {
  return (u32)(size_t)(const __attribute__((address_space(3))) void*)p;
}

// Inline-asm ds_read_b128: invisible to the compiler's waitcnt-insertion pass.
// Caller supplies ordering: counted vmcnt + barrier for RAW, and an explicit
// s_waitcnt lgkmcnt(0) + sched_barrier(0) before consuming (rule #18).
template <int IMM>
__device__ __forceinline__ bf16x8 dsr16(u32 a) {
  bf16x8 r;
  asm volatile("ds_read_b128 %0, %1 offset:%2" : "=v"(r) : "v"(a), "n"(IMM));
  return r;
}

// Row-chunk XCD swizzle (used by gemm_bt/QKV).
__device__ __forceinline__ void xcd_swizzle(int gx, int gy, int& bx, int& by) {
  int nwg = gx * gy;
  int lin = blockIdx.x + gx * blockIdx.y;
  int q = nwg >> 3;
  int nl = (lin & 7) * q + (lin >> 3);
  bx = nl % gx;
  by = nl / gx;
}

// 2-D TILED XCD swizzle: each XCD owns a TX x TY block-tile (round-7: cut
// FFN1 FETCH 37.4 -> 25.1 MB).  Requires gx%TX==0 and (nwg/8)%TX==0.
template <int TX>
__device__ __forceinline__ void xcd_tile_swizzle(int gx, int gy, int& bx, int& by) {
  int nwg = gx * gy;
  int lin = blockIdx.x + gx * blockIdx.y;
  int c = lin & 7;          // XCD id
  int wdx = lin >> 3;       // index within XCD chunk
  int q = nwg >> 3;
  int TY = q / TX;
  int ncx = gx / TX;        // XCD tile columns
  int xt = c % ncx, yt = c / ncx;
  bx = xt * TX + wdx % TX;
  by = yt * TY + wdx / TX;
}

// ---------------- weight transpose + fp32->bf16 ----------------
// W [K,N] fp32 -> WT [N,K] bf16 (generic, for W1/W2)
__global__ __launch_bounds__(256)
void wtrans_kernel(const float* __restrict__ W, u16* __restrict__ WT, int K, int N) {
  __shared__ float tile[32][33];
  int tx = threadIdx.x & 31, ty = threadIdx.x >> 5;
  int n0 = blockIdx.x * 32, k0 = blockIdx.y * 32;
#pragma unroll
  for (int i = 0; i < 32; i += 8)
    tile[ty + i][tx] = W[(size_t)(k0 + ty + i) * N + (n0 + tx)];
  __syncthreads();
#pragma unroll
  for (int i = 0; i < 32; i += 8)
    WT[(size_t)(n0 + ty + i) * K + (k0 + tx)] = f2bf(tile[tx][ty + i]);
}

// 4 square [1024x1024] weights in one dispatch: z=0..2 -> WqkvT rows, z=3 -> WoT
__global__ __launch_bounds__(256)
void wtrans4_kernel(const float* __restrict__ W0, const float* __restrict__ W1_,
                    const float* __restrict__ W2_, const float* __restrict__ W3,
                    u16* __restrict__ Dqkv, u16* __restrict__ Do) {
  __shared__ float tile[32][33];
  int z = blockIdx.z;
  const float* W = (z == 0) ? W0 : (z == 1) ? W1_ : (z == 2) ? W2_ : W3;
  u16* D = (z < 3) ? (Dqkv + (size_t)z * EMB * EMB) : Do;
  int tx = threadIdx.x & 31, ty = threadIdx.x >> 5;
  int n0 = blockIdx.x * 32, k0 = blockIdx.y * 32;
#pragma unroll
  for (int i = 0; i < 32; i += 8)
    tile[ty + i][tx] = W[(size_t)(k0 + ty + i) * EMB + (n0 + tx)];
  __syncthreads();
#pragma unroll
  for (int i = 0; i < 32; i += 8)
    D[(size_t)(n0 + ty + i) * EMB + (k0 + tx)] = f2bf(tile[tx][ty + i]);
}

// ---------------- V transpose per head: QKV [B*S,3072] (V at col 2048+h*64)
// -> Vt [B*H, 64, SEQ]
__global__ __launch_bounds__(256)
void vtrans_kernel(const u16* __restrict__ QKV, u16* __restrict__ Vt) {
  __shared__ u16 tile[64 * 72];
  int bh = blockIdx.y, b = bh >> 4, h = bh & 15;
  int s0 = blockIdx.x * 64;
  const u16* src = QKV + (size_t)b * SEQ * QKVLD + 2048 + (size_t)h * HDIM;
  int tid = threadIdx.x;
#pragma unroll
  for (int cc = 0; cc < 2; ++cc) {
    int c = tid + cc * 256;
    int s = c >> 3, d0 = (c & 7) * 8;
    uint4 v = *(const uint4*)(src + (size_t)(s0 + s) * QKVLD + d0);
    *(uint4*)(&tile[s * 72 + d0]) = v;
  }
  __syncthreads();
  u16* dst = Vt + (size_t)bh * HDIM * SEQ;
#pragma unroll
  for (int cc = 0; cc < 2; ++cc) {
    int c = tid + cc * 256;
    int d = c >> 3, t0l = (c & 7) * 8;
    union { uint4 u; u16 s[8]; } ou;
#pragma unroll
    for (int j = 0; j < 8; ++j) ou.s[j] = tile[(t0l + j) * 72 + d];
    *(uint4*)(dst + (size_t)d * SEQ + s0 + t0l) = ou.u;
  }
}

// ---------------- layernorm: 1 row per wave, 4 rows per block ----------------
__global__ __launch_bounds__(256)
void ln_kernel(const float* __restrict__ in, const float* __restrict__ gamma,
               const float* __restrict__ beta, u16* __restrict__ outb) {
  int w = threadIdx.x >> 6, lane = threadIdx.x & 63;
  int row = blockIdx.x * 4 + w;
  size_t base = (size_t)row * EMB;
  float4 v[4];
  float s = 0.f, q = 0.f;
#pragma unroll
  for (int j = 0; j < 4; ++j) {
    v[j] = *(const float4*)(in + base + j * 256 + lane * 4);
    s += v[j].x + v[j].y + v[j].z + v[j].w;
    q += v[j].x * v[j].x + v[j].y * v[j].y + v[j].z * v[j].z + v[j].w * v[j].w;
  }
#pragma unroll
  for (int off = 1; off < 64; off <<= 1) {
    s += __shfl_xor(s, off);
    q += __shfl_xor(q, off);
  }
  float mean = s * (1.0f / EMB);
  float var = q * (1.0f / EMB) - mean * mean;
  float rstd = rsqrtf(var + 1e-5f);
#pragma unroll
  for (int j = 0; j < 4; ++j) {
    int c = j * 256 + lane * 4;
    float4 g4 = *(const float4*)(gamma + c);
    float4 b4 = *(const float4*)(beta + c);
    ushort4 ob;
    ob.x = f2bf((v[j].x - mean) * rstd * g4.x + b4.x);
    ob.y = f2bf((v[j].y - mean) * rstd * g4.y + b4.y);
    ob.z = f2bf((v[j].z - mean) * rstd * g4.z + b4.z);
    ob.w = f2bf((v[j].w - mean) * rstd * g4.w + b4.w);
    *(ushort4*)(outb + base + c) = ob;
  }
}

// ---------------- LN2 fused with Wo split-K reduce ----------------
// in = p[0]+p[pstride]+bias(col)+resid; layernorm(in) -> bf16 + fp32
__global__ __launch_bounds__(256)
void ln2f_kernel(const float* __restrict__ p, size_t pstride,
                 const float* __restrict__ bias, const float* __restrict__ resid,
                 const float* __restrict__ gamma, const float* __restrict__ beta,
                 u16* __restrict__ outb, float* __restrict__ outf) {
  int w = threadIdx.x >> 6, lane = threadIdx.x & 63;
  int row = blockIdx.x * 4 + w;
  size_t base = (size_t)row * EMB;
  float4 v[4];
  float s = 0.f, q = 0.f;
#pragma unroll
  for (int j = 0; j < 4; ++j) {
    int c = j * 256 + lane * 4;
    float4 a = *(const float4*)(p + base + c);
    float4 b = *(const float4*)(p + pstride + base + c);
    float4 r = *(const float4*)(resid + base + c);
    float4 bb = *(const float4*)(bias + c);
    v[j].x = a.x + b.x + r.x + bb.x;
    v[j].y = a.y + b.y + r.y + bb.y;
    v[j].z = a.z + b.z + r.z + bb.z;
    v[j].w = a.w + b.w + r.w + bb.w;
    s += v[j].x + v[j].y + v[j].z + v[j].w;
    q += v[j].x * v[j].x + v[j].y * v[j].y + v[j].z * v[j].z + v[j].w * v[j].w;
  }
#pragma unroll
  for (int off = 1; off < 64; off <<= 1) {
    s += __shfl_xor(s, off);
    q += __shfl_xor(q, off);
  }
  float mean = s * (1.0f / EMB);
  float var = q * (1.0f / EMB) - mean * mean;
  float rstd = rsqrtf(var + 1e-5f);
#pragma unroll
  for (int j = 0; j < 4; ++j) {
    int c = j * 256 + lane * 4;
    float4 g4 = *(const float4*)(gamma + c);
    float4 b4 = *(const float4*)(beta + c);
    float y0 = (v[j].x - mean) * rstd * g4.x + b4.x;
    float y1 = (v[j].y - mean) * rstd * g4.y + b4.y;
    float y2 = (v[j].z - mean) * rstd * g4.z + b4.z;
    float y3 = (v[j].w - mean) * rstd * g4.w + b4.w;
    ushort4 ob;
    ob.x = f2bf(y0); ob.y = f2bf(y1); ob.z = f2bf(y2); ob.w = f2bf(y3);
    *(ushort4*)(outb + base + c) = ob;
    *(float4*)(outf + base + c) = make_float4(y0, y1, y2, y3);
  }
}

// ---------------- split-K reduce: out = p[z0]+p[z1]+bias+resid (fp32) --------
__global__ __launch_bounds__(256)
void reduce2_kernel(const float* __restrict__ p, size_t pstride,
                    const float* __restrict__ bias, const float* __restrict__ resid,
                    float* __restrict__ out, int ncols) {
  size_t i = ((size_t)blockIdx.x * 256 + threadIdx.x) * 4;
  float4 a = *(const float4*)(p + i);
  float4 b = *(const float4*)(p + pstride + i);
  float4 r = *(const float4*)(resid + i);
  int col = (int)(i & (size_t)(ncols - 1));
  float4 bb = *(const float4*)(bias + col);
  float4 o;
  o.x = a.x + b.x + r.x + bb.x;
  o.y = a.y + b.y + r.y + bb.y;
  o.z = a.z + b.z + r.z + bb.z;
  o.w = a.w + b.w + r.w + bb.w;
  *(float4*)(out + i) = o;
}

// ---------------- GEMM (round-0 structure): C[M,N] = A*BT^T, 128x128 tile ----
// 256 threads, 32KB LDS -> 4 resident blocks/CU; per-K-step full drain is
// hidden by cross-block overlap (m114 mechanism).  + row-chunk XCD swizzle.
__global__ __launch_bounds__(256)
void gemm_bt(const u16* __restrict__ A, const u16* __restrict__ BT,
             const float* __restrict__ bias, const float* __restrict__ bias2,
             const float* __restrict__ bias3, void* __restrict__ out,
             const float* __restrict__ resid, int M, int N, int K,
             int mode, float scale, int ksplit,
             float* __restrict__ partial, size_t pstride) {
  __shared__ __align__(16) u16 As[128 * 64];
  __shared__ __align__(16) u16 Bs[128 * 64];
  int tid = threadIdx.x;
  int lane = tid & 63, w = tid >> 6;
  int wm = w >> 1, wn = w & 1;
  int g = lane >> 4, lr = lane & 15;
  int bx, by;
  xcd_swizzle(gridDim.x, gridDim.y, bx, by);
  int m0 = by * 128, n0 = bx * 128;
  int z = blockIdx.z;
  int kbeg = z * ksplit, kend = kbeg + ksplit;

  f32x4 acc[4][4];
#pragma unroll
  for (int mt = 0; mt < 4; ++mt)
#pragma unroll
    for (int nt = 0; nt < 4; ++nt) {
      acc[mt][nt][0] = 0.f; acc[mt][nt][1] = 0.f;
      acc[mt][nt][2] = 0.f; acc[mt][nt][3] = 0.f;
    }

  size_t ao[4], bo_[4];
  int lo[4];
#pragma unroll
  for (int cc = 0; cc < 4; ++cc) {
    int c = tid + cc * 256;
    int row = c >> 3, slot = c & 7;
    int gc = slot ^ (row & 7);
    ao[cc] = (size_t)(m0 + row) * K + gc * 8;
    bo_[cc] = (size_t)(n0 + row) * K + gc * 8;
    lo[cc] = c * 8;
  }
  int swz[2];
#pragma unroll
  for (int kk = 0; kk < 2; ++kk) swz[kk] = ((kk * 4 + g) ^ (lr & 7)) * 8;

  for (int k0 = kbeg; k0 < kend; k0 += 64) {
    __syncthreads();
#pragma unroll
    for (int cc = 0; cc < 4; ++cc) gload16(A + ao[cc] + k0, As + lo[cc]);
#pragma unroll
    for (int cc = 0; cc < 4; ++cc) gload16(BT + bo_[cc] + k0, Bs + lo[cc]);
    __syncthreads();
#pragma unroll
    for (int kk = 0; kk < 2; ++kk) {
      bf16x8 af[4], bfr[4];
#pragma unroll
      for (int mt = 0; mt < 4; ++mt)
        af[mt] = *(const bf16x8*)(As + (wm * 64 + mt * 16 + lr) * 64 + swz[kk]);
#pragma unroll
      for (int nt = 0; nt < 4; ++nt)
        bfr[nt] = *(const bf16x8*)(Bs + (wn * 64 + nt * 16 + lr) * 64 + swz[kk]);
#pragma unroll
      for (int mt = 0; mt < 4; ++mt)
#pragma unroll
        for (int nt = 0; nt < 4; ++nt)
          acc[mt][nt] = __builtin_amdgcn_mfma_f32_16x16x32_bf16(af[mt], bfr[nt], acc[mt][nt], 0, 0, 0);
    }
  }

  float* pz = partial + (size_t)z * pstride;
#pragma unroll
  for (int mt = 0; mt < 4; ++mt) {
    int row = m0 + wm * 64 + mt * 16 + g * 4;
#pragma unroll
    for (int nt = 0; nt < 4; ++nt) {
      int col = n0 + wn * 64 + nt * 16 + lr;
      float bcol;
      if (mode == 3) {
        int which = col >> 10;
        const float* bp = (which == 0) ? bias : (which == 1) ? bias2 : bias3;
        bcol = bp[col & 1023];
      } else if (mode != 4) {
        bcol = bias[col];
      } else {
        bcol = 0.f;
      }
#pragma unroll
      for (int r = 0; r < 4; ++r) {
        float vacc = acc[mt][nt][r] + bcol;
        size_t idx = (size_t)(row + r) * N + col;
        if (mode == 0)      ((u16*)out)[idx] = f2bf(vacc * scale);
        else if (mode == 1) ((u16*)out)[idx] = f2bf(geluf(vacc));
        else if (mode == 2) ((float*)out)[idx] = vacc + resid[idx];
        else if (mode == 3) ((u16*)out)[idx] = f2bf(col < 1024 ? vacc * QSCALE : vacc);
        else                pz[idx] = vacc;
      }
    }
  }
}

// ====================================================================
// gemm8n<TXS>: 128x128 tile, BK=64, 256 threads (4 waves, 2M x 2N),
// 8-phase / 2-K-tile counted-vmcnt ring (same verified ring as gemm8) at
// 64 KB LDS -> **2 blocks/CU**: pipelined schedule AND cross-block overlap
// (m114) stacked -- the one configuration not yet measured.  Per (d,kh)
// sub-buffer = 128x32 u16 for BOTH A and B; paired-row swizzle; 2 gload16
// per half-tile per thread; steady vmcnt(6) = 3 half-tiles in flight.
// ====================================================================

#define BARM __builtin_amdgcn_s_barrier()
#define VMW6 asm volatile("s_waitcnt vmcnt(6)")
#define VMW0 asm volatile("s_waitcnt vmcnt(0)")
#define NOSTG ((void)0)
#define NOWT ((void)0)
#define NABUF (128 * 32)

#define STGN_A(t, d, kh)                                                      \
  { gload16(A + (size_t)sgA[0] + kbeg + (t) * 64 + (kh) * 32,                 \
            As + ((d) * 2 + (kh)) * NABUF + sl[0]);                           \
    gload16(A + (size_t)sgA[1] + kbeg + (t) * 64 + (kh) * 32,                 \
            As + ((d) * 2 + (kh)) * NABUF + sl[1]); }

#define STGN_B(t, d, kh)                                                      \
  { gload16(BT + (size_t)sgB[0] + kbeg + (t) * 64 + (kh) * 32,                \
            Bs + ((d) * 2 + (kh)) * NABUF + sl[0]);                           \
    gload16(BT + (size_t)sgB[1] + kbeg + (t) * 64 + (kh) * 32,                \
            Bs + ((d) * 2 + (kh)) * NABUF + sl[1]); }

#define PHASEN(d, kk, mh, STAGE, WAITC)                                       \
  {                                                                           \
    const u32 bA = bB + ((d) * 2 + (kk)) * (NABUF * 2);                       \
    const u32 aA = aB + ((d) * 2 + (kk)) * (NABUF * 2);                       \
    if ((mh) == 0) {                                                          \
      bfr[0] = dsr16<0>(bA);                                                  \
      bfr[1] = dsr16<1024>(bA);                                               \
      bfr[2] = dsr16<2048>(bA);                                               \
      bfr[3] = dsr16<3072>(bA);                                               \
    }                                                                         \
    bf16x8 af[2];                                                             \
    af[0] = dsr16<(((mh) * 2 + 0) * 1024)>(aA);                               \
    af[1] = dsr16<(((mh) * 2 + 1) * 1024)>(aA);                               \
    STAGE;                                                                    \
    BARM;                                                                     \
    asm volatile("s_waitcnt lgkmcnt(0)");                                     \
    __builtin_amdgcn_sched_barrier(0);                                        \
    __builtin_amdgcn_s_setprio(1);                                            \
    _Pragma("unroll")                                                         \
    for (int mi = 0; mi < 2; ++mi)                                            \
      _Pragma("unroll")                                                       \
      for (int nt = 0; nt < 4; ++nt)                                          \
        acc[(mh) * 2 + mi][nt] = __builtin_amdgcn_mfma_f32_16x16x32_bf16(     \
            af[mi], bfr[nt], acc[(mh) * 2 + mi][nt], 0, 0, 0);                \
    __builtin_amdgcn_s_setprio(0);                                            \
    WAITC;                                                                    \
    BARM;                                                                     \
  }

template <int TXS>
__global__ __launch_bounds__(256, 2)
void gemm8n(const u16* __restrict__ A, const u16* __restrict__ BT,
            const float* __restrict__ bias, const float* __restrict__ bias2,
            const float* __restrict__ bias3, void* __restrict__ out,
            const float* __restrict__ resid, int M, int N, int K,
            int mode, float scale, int ksplit,
            float* __restrict__ partial, size_t pstride) {
  __shared__ __align__(16) u16 As[4 * NABUF];   // 32 KB
  __shared__ __align__(16) u16 Bs[4 * NABUF];   // 32 KB
  int tid = threadIdx.x;
  int lane = tid & 63, w = tid >> 6;
  int wm = w >> 1, wn = w & 1;
  int g = lane >> 4, lr = lane & 15;
  int bx, by;
  xcd_tile_swizzle<TXS>(gridDim.x, gridDim.y, bx, by);
  int m0 = by * 128, n0 = bx * 128;
  int z = blockIdx.z;
  size_t kbeg = (size_t)z * ksplit;
  int nk = ksplit >> 6, npair = nk >> 1;

  // frag ds_read byte bases; phys slot is a pure lane function
  int phys = ((lr & 1) * 4 + g) ^ ((lr >> 1) & 7);
  int aoff = wm * 64 * 32 + (lr >> 1) * 64 + phys * 8;   // u16 units
  int boff = wn * 64 * 32 + (lr >> 1) * 64 + phys * 8;
  const u32 aB = lds_addr(As) + 2 * aoff;
  const u32 bB = lds_addr(Bs) + 2 * boff;

  // staging: LDS linear (c*16B), global pre-swizzled (paired-row)
  int sgA[2], sgB[2], sl[2];
#pragma unroll
  for (int j = 0; j < 2; ++j) {
    int c = tid + j * 256;
    int sr = c >> 3, ph = c & 7, l = ph ^ (sr & 7);
    sgA[j] = (m0 + 2 * sr + (l >> 2)) * K + (l & 3) * 8;
    sgB[j] = (n0 + 2 * sr + (l >> 2)) * K + (l & 3) * 8;
    sl[j] = c * 8;
  }

  f32x4 acc[4][4];
#pragma unroll
  for (int mt = 0; mt < 4; ++mt)
#pragma unroll
    for (int nt = 0; nt < 4; ++nt) {
      acc[mt][nt][0] = 0.f; acc[mt][nt][1] = 0.f;
      acc[mt][nt][2] = 0.f; acc[mt][nt][3] = 0.f;
    }

  bf16x8 bfr[4];

  // prologue: T0 complete (8 loads) + first 3 half-tiles of T1 (6 loads)
  STGN_B(0, 0, 0); STGN_A(0, 0, 0); STGN_B(0, 0, 1); STGN_A(0, 0, 1);
  STGN_B(1, 1, 0); STGN_A(1, 1, 0); STGN_B(1, 1, 1);
  VMW6; BARM;

  for (int it = 0; it < npair - 1; ++it) {
    int t1 = 2 * it + 1, t2 = 2 * it + 2, t3 = 2 * it + 3;
    PHASEN(0, 0, 0, STGN_A(t1, 1, 1), NOWT)
    PHASEN(0, 0, 1, STGN_B(t2, 0, 0), NOWT)
    PHASEN(0, 1, 0, STGN_A(t2, 0, 0), NOWT)
    PHASEN(0, 1, 1, STGN_B(t2, 0, 1), VMW6)
    PHASEN(1, 0, 0, STGN_A(t2, 0, 1), NOWT)
    PHASEN(1, 0, 1, STGN_B(t3, 1, 0), NOWT)
    PHASEN(1, 1, 0, STGN_A(t3, 1, 0), NOWT)
    PHASEN(1, 1, 1, STGN_B(t3, 1, 1), VMW6)
  }
  {  // peeled last pair: only the final A(k1) half-tile left to issue
    int t1 = nk - 1;
    PHASEN(0, 0, 0, STGN_A(t1, 1, 1), NOWT)
    PHASEN(0, 0, 1, NOSTG, NOWT)
    PHASEN(0, 1, 0, NOSTG, NOWT)
    PHASEN(0, 1, 1, NOSTG, VMW0)
    PHASEN(1, 0, 0, NOSTG, NOWT)
    PHASEN(1, 0, 1, NOSTG, NOWT)
    PHASEN(1, 1, 0, NOSTG, NOWT)
    PHASEN(1, 1, 1, NOSTG, NOWT)
  }

  // epilogue
  float* pz = partial + (size_t)z * pstride;
#pragma unroll
  for (int mt = 0; mt < 4; ++mt) {
    int row = m0 + wm * 64 + mt * 16 + g * 4;
#pragma unroll
    for (int nt = 0; nt < 4; ++nt) {
      int col = n0 + wn * 64 + nt * 16 + lr;
      float bcol;
      if (mode == 3) {
        int which = col >> 10;
        const float* bp = (which == 0) ? bias : (which == 1) ? bias2 : bias3;
        bcol = bp[col & 1023];
      } else if (mode != 4) {
        bcol = bias[col];
      } else {
        bcol = 0.f;
      }
#pragma unroll
      for (int r = 0; r < 4; ++r) {
        float vacc = acc[mt][nt][r] + bcol;
        size_t idx = (size_t)(row + r) * N + col;
        if (mode == 0)      ((u16*)out)[idx] = f2bf(vacc * scale);
        else if (mode == 1) ((u16*)out)[idx] = f2bf(geluf(vacc));
        else if (mode == 2) ((float*)out)[idx] = vacc + resid[idx];
        else if (mode == 3) ((u16*)out)[idx] = f2bf(col < 1024 ? vacc * QSCALE : vacc);
        else                pz[idx] = vacc;
      }
    }
  }
}

// ---------------- flash attention, paired q-tiles, no-max exp2 softmax -------
// (round-5 known-good structure)
__shared__ __align__(16) u16 attn_Kt[64 * 64];
__shared__ __align__(16) u16 attn_VT[64 * 64];
__shared__ __align__(16) u16 attn_Pw[2][4][16 * PWS];

template <int S0>
__device__ __forceinline__ void attn_tile(
    int t0, const int* q0, int w, int g, int lr, const bf16x8& ones,
    bf16x8 (&qf)[2][2], f32x4 (&lacc)[2], f32x4 (&oacc)[2][4]) {
  f32x4 sacc[2][4];
#pragma unroll
  for (int s = S0; s < 2; ++s)
#pragma unroll
    for (int nt = 0; nt < 4; ++nt) {
      sacc[s][nt][0] = 0.f; sacc[s][nt][1] = 0.f;
      sacc[s][nt][2] = 0.f; sacc[s][nt][3] = 0.f;
    }
#pragma unroll
  for (int kk = 0; kk < 2; ++kk)
#pragma unroll
    for (int nt = 0; nt < 4; ++nt) {
      int sw = ((kk * 4 + g) ^ lr) & 7;
      bf16x8 bfr = *(const bf16x8*)(&attn_Kt[(nt * 16 + lr) * 64 + sw * 8]);
      if (S0 == 0)
        sacc[0][nt] = __builtin_amdgcn_mfma_f32_16x16x32_bf16(qf[0][kk], bfr, sacc[0][nt], 0, 0, 0);
      sacc[1][nt] = __builtin_amdgcn_mfma_f32_16x16x32_bf16(qf[1][kk], bfr, sacc[1][nt], 0, 0, 0);
    }

#pragma unroll
  for (int s = S0; s < 2; ++s) {
    bool diag = (t0 == q0[s]);  // wave-uniform
#pragma unroll
    for (int r = 0; r < 4; ++r) {
#pragma unroll
      for (int nt = 0; nt < 4; ++nt) {
        float pv = ex2(sacc[s][nt][r]);
        if (diag && (nt * 16 + lr > w * 16 + g * 4 + r)) pv = 0.f;
        attn_Pw[s][w][(g * 4 + r) * PWS + nt * 16 + lr] = f2bf(pv);
      }
    }
  }

#pragma unroll
  for (int kk = 0; kk < 2; ++kk) {
    bf16x8 pf0, pf1;
    if (S0 == 0) pf0 = *(const bf16x8*)(&attn_Pw[0][w][lr * PWS + kk * 32 + g * 8]);
    pf1 = *(const bf16x8*)(&attn_Pw[1][w][lr * PWS + kk * 32 + g * 8]);
#pragma unroll
    for (int nt = 0; nt < 4; ++nt) {
      int sw = ((kk * 4 + g) ^ lr) & 7;
      bf16x8 vf = *(const bf16x8*)(&attn_VT[(nt * 16 + lr) * 64 + sw * 8]);
      if (S0 == 0)
        oacc[0][nt] = __builtin_amdgcn_mfma_f32_16x16x32_bf16(pf0, vf, oacc[0][nt], 0, 0, 0);
      oacc[1][nt] = __builtin_amdgcn_mfma_f32_16x16x32_bf16(pf1, vf, oacc[1][nt], 0, 0, 0);
    }
    if (S0 == 0)
      lacc[0] = __builtin_amdgcn_mfma_f32_16x16x32_bf16(pf0, ones, lacc[0], 0, 0, 0);
    lacc[1] = __builtin_amdgcn_mfma_f32_16x16x32_bf16(pf1, ones, lacc[1], 0, 0, 0);
  }
}

__global__ __launch_bounds__(256)
void attn2_kernel(const u16* __restrict__ QKV, const u16* __restrict__ Vt,
                  u16* __restrict__ ctx) {
  int tid = threadIdx.x, lane = tid & 63, w = tid >> 6;
  int g = lane >> 4, lr = lane & 15;
  int bh = blockIdx.y, b = bh >> 4, h = bh & 15;
  int q0[2];
  q0[0] = blockIdx.x * 64;
  q0[1] = (SEQ / 64 - 1 - blockIdx.x) * 64;
  const u16* Qh = QKV + (size_t)b * SEQ * QKVLD + (size_t)h * HDIM;
  const u16* Kh = Qh + 1024;
  const u16* Vth = Vt + (size_t)bh * HDIM * SEQ;

  bf16x8 ones;
#pragma unroll
  for (int j = 0; j < 8; ++j) ones[j] = (__bf16)1.0f;

  bf16x8 qf[2][2];
#pragma unroll
  for (int s = 0; s < 2; ++s)
#pragma unroll
    for (int kk = 0; kk < 2; ++kk)
      qf[s][kk] = *(const bf16x8*)(Qh + (size_t)(q0[s] + w * 16 + lr) * QKVLD + kk * 32 + g * 8);

  f32x4 lacc[2];
  f32x4 oacc[2][4];
#pragma unroll
  for (int s = 0; s < 2; ++s) {
    lacc[s][0] = 0.f; lacc[s][1] = 0.f; lacc[s][2] = 0.f; lacc[s][3] = 0.f;
#pragma unroll
    for (int nt = 0; nt < 4; ++nt) {
      oacc[s][nt][0] = 0.f; oacc[s][nt][1] = 0.f;
      oacc[s][nt][2] = 0.f; oacc[s][nt][3] = 0.f;
    }
  }

  int c1 = tid, c2 = tid + 256;
  int t1 = c1 >> 3, ch1 = (c1 ^ t1) & 7;
  int t2 = c2 >> 3, ch2 = (c2 ^ t2) & 7;
  for (int t0 = 0; t0 <= q0[1]; t0 += 64) {
    __syncthreads();
    gload16(Kh + (size_t)(t0 + t1) * QKVLD + ch1 * 8, attn_Kt + c1 * 8);
    gload16(Kh + (size_t)(t0 + t2) * QKVLD + ch2 * 8, attn_Kt + c2 * 8);
    gload16(Vth + (size_t)t1 * SEQ + t0 + ch1 * 8, attn_VT + c1 * 8);
    gload16(Vth + (size_t)t2 * SEQ + t0 + ch2 * 8, attn_VT + c2 * 8);
    __syncthreads();

    if (t0 <= q0[0])
      attn_tile<0>(t0, q0, w, g, lr, ones, qf, lacc, oacc);
    else
      attn_tile<1>(t0, q0, w, g, lr, ones, qf, lacc, oacc);
  }

#pragma unroll
  for (int s = 0; s < 2; ++s) {
    int srow = q0[s] + w * 16 + g * 4;
    float inv[4];
#pragma unroll
    for (int r = 0; r < 4; ++r) inv[r] = 1.0f / lacc[s][r];
#pragma unroll
    for (int nt = 0; nt < 4; ++nt) {
      int col = h * HDIM + nt * 16 + lr;
#pragma unroll
      for (int r = 0; r < 4; ++r) {
        float o = oacc[s][nt][r] * inv[r];
        ctx[((size_t)b * SEQ + srow + r) * EMB + col] = f2bf(o);
      }
    }
  }
}

// ---------------- launch ----------------
extern "C" void kernel_launch(void* const* d_in, const int* in_sizes, int n_in,
                              void* d_out, int out_size, void* d_ws, size_t ws_size,
                              hipStream_t stream) {
  const float* x    = (const float*)d_in[0];
  const float* Wq   = (const float*)d_in[2];
  const float* bq   = (const float*)d_in[3];
  const float* Wk   = (const float*)d_in[4];
  const float* bk   = (const float*)d_in[5];
  const float* Wv   = (const float*)d_in[6];
  const float* bv   = (const float*)d_in[7];
  const float* Wo   = (const float*)d_in[8];
  const float* bo   = (const float*)d_in[9];
  const float* W1   = (const float*)d_in[10];
  const float* b1   = (const float*)d_in[11];
  const float* W2   = (const float*)d_in[12];
  const float* b2   = (const float*)d_in[13];
  const float* ln1g = (const float*)d_in[14];
  const float* ln1b = (const float*)d_in[15];
  const float* ln2g = (const float*)d_in[16];
  const float* ln2b = (const float*)d_in[17];

  char* ws = (char*)d_ws;
  u16* WqkvT = (u16*)(ws + ((size_t)0 << 20));
  u16* WoT   = (u16*)(ws + ((size_t)6 << 20));
  u16* W1T   = (u16*)(ws + ((size_t)8 << 20));
  u16* W2T   = (u16*)(ws + ((size_t)16 << 20));
  u16* xb    = (u16*)(ws + ((size_t)24 << 20));
  u16* QKVb  = (u16*)(ws + ((size_t)32 << 20));
  u16* ctxb  = (u16*)(ws + ((size_t)56 << 20));
  float* x2f = (float*)(ws + ((size_t)48 << 20));
  u16* x2b   = xb;
  u16* VtG   = (u16*)(ws + ((size_t)64 << 20));
  float* pWo = (float*)(ws + ((size_t)64 << 20));  // 2 x 16MB partials
  u16* h1    = (u16*)(ws + ((size_t)64 << 20));    // 32MB
  float* pF2 = (float*)(ws + ((size_t)0 << 20));   // z0 at 0-16; z1 at 32-48

  dim3 blk(256);
  const int M = NBATCH * SEQ; // 4096

  // weight transposes (fp32 -> bf16, [K,N] -> [N,K])
  wtrans4_kernel<<<dim3(32, 32, 4), blk, 0, stream>>>(Wq, Wk, Wv, Wo, WqkvT, WoT);
  wtrans_kernel<<<dim3(128, 32), blk, 0, stream>>>(W1, W1T, EMB, FFDIM);
  wtrans_kernel<<<dim3(32, 128), blk, 0, stream>>>(W2, W2T, FFDIM, EMB);

  // LN1
  ln_kernel<<<M / 4, blk, 0, stream>>>(x, ln1g, ln1b, xb);

  // fused QKV projection: gemm_bt (768 blocks, ~4 resident/CU) + XCD swizzle
  gemm_bt<<<dim3(QKVLD / 128, M / 128), blk, 0, stream>>>(
      xb, WqkvT, bq, bk, bv, QKVb, nullptr, M, QKVLD, EMB, 3, 1.0f, EMB, nullptr, 0);

  // V^T per head
  vtrans_kernel<<<dim3(SEQ / 64, NBATCH * NHEAD), blk, 0, stream>>>(QKVb, VtG);

  // attention (paired q-tiles: uniform 33 iterations/block)
  attn2_kernel<<<dim3(SEQ / 128, NBATCH * NHEAD), blk, 0, stream>>>(QKVb, VtG, ctxb);

  // output projection: gemm8n (grid 8x32x2 = 512 blocks, 2/CU), split-K=2
  gemm8n<4><<<dim3(EMB / 128, M / 128, 2), blk, 0, stream>>>(
      ctxb, WoT, nullptr, nullptr, nullptr, nullptr, nullptr, M, EMB, EMB, 4, 1.0f,
      EMB / 2, pWo, (size_t)4 << 20);

  // LN2 fused with Wo reduce (+bo+x residual) -> x2f fp32 + x2b bf16
  ln2f_kernel<<<M / 4, blk, 0, stream>>>(pWo, (size_t)4 << 20, bo, x, ln2g, ln2b,
                                         x2b, x2f);

  // FFN1 + fast GELU: gemm8n (grid 32x32 = 1024 blocks, 2/CU)
  gemm8n<8><<<dim3(FFDIM / 128, M / 128), blk, 0, stream>>>(
      x2b, W1T, b1, nullptr, nullptr, h1, nullptr, M, FFDIM, EMB, 1, 1.0f, EMB,
      nullptr, 0);

  // FFN2: gemm8n split-K=2 (grid 8x32x2 = 512 blocks, 2/CU)
  gemm8n<4><<<dim3(EMB / 128, M / 128, 2), blk, 0, stream>>>(
      h1, W2T, nullptr, nullptr, nullptr, nullptr, nullptr, M, EMB, FFDIM, 4, 1.0f,
      FFDIM / 2, pF2, (size_t)8 << 20);
  // d_out = p0 + p1 + b2 + x2f
  reduce2_kernel<<<M * EMB / 1024, blk, 0, stream>>>(pF2, (size_t)8 << 20, b2, x2f,
                                                     (float*)d_out, EMB);
}

// Round 9
// 395.814 us; speedup vs baseline: 1.0465x; 1.0230x over previous
//
#include <hip/hip_runtime.h>
#include <cmath>

typedef unsigned short u16;
typedef unsigned int u32;
typedef __bf16 bf16x8 __attribute__((ext_vector_type(8)));
typedef float f32x4 __attribute__((ext_vector_type(4)));

#define SEQ 2048
#define EMB 1024
#define NHEAD 16
#define HDIM 64
#define FFDIM 4096
#define NBATCH 2
#define QKVLD 3072  // fused QKV row stride
#define PWS 68      // attn Pw row stride (u16)

// Q pre-scale folds 1/sqrt(64) and 1/ln(2) so softmax uses exp2 directly.
#define QSCALE 0.18033688011112042f

__device__ __forceinline__ u16 f2bf(float f) {
  u32 u = __float_as_uint(f);
  u32 r = u + 0x7fffu + ((u >> 16) & 1u);
  return (u16)(r >> 16);
}

__device__ __forceinline__ float ex2(float x) {
#if __has_builtin(__builtin_amdgcn_exp2f)
  return __builtin_amdgcn_exp2f(x);
#else
  return exp2f(x);
#endif
}

// tanh-form GELU via a single exp2: gelu(x) = x * sigmoid(2u),
// u = 0.7978845608*(x + 0.044715 x^3).  max |err| vs exact erf ~3e-3.
__device__ __forceinline__ float geluf(float x) {
  float u = 0.7978845608028654f * (x + 0.044715f * x * x * x);
  float e = ex2(2.8853900817779268f * u);  // exp(2u)
  return x - x / (e + 1.0f);
}

// async global->LDS, 16B per lane. LDS dest must be wave-uniform base + lane*16.
__device__ __forceinline__ void gload16(const void* g, void* l) {
  __builtin_amdgcn_global_load_lds(
      (const __attribute__((address_space(1))) unsigned int*)g,
      (__attribute__((address_space(3))) unsigned int*)l, 16, 0, 0);
}

// 32-bit LDS byte address for inline-asm ds ops.
__device__ __forceinline__ u32 lds_addr(const void* p) {
  return (u32)(size_t)(const __attribute__((address_space(3))) void*)p;
}

// Inline-asm ds_read_b128: invisible to the compiler's waitcnt-insertion pass.
// Caller supplies ordering: counted vmcnt + barrier for RAW, and an explicit
// s_waitcnt lgkmcnt(0) + sched_barrier(0) before consuming (rule #18).
template <int IMM>
__device__ __forceinline__ bf16x8 dsr16(u32 a) {
  bf16x8 r;
  asm volatile("ds_read_b128 %0, %1 offset:%2" : "=v"(r) : "v"(a), "n"(IMM));
  return r;
}

// Row-chunk XCD swizzle (round-5 known-good).
__device__ __forceinline__ void xcd_swizzle(int gx, int gy, int& bx, int& by) {
  int nwg = gx * gy;
  int lin = blockIdx.x + gx * blockIdx.y;
  int q = nwg >> 3;
  int nl = (lin & 7) * q + (lin >> 3);
  bx = nl % gx;
  by = nl / gx;
}

// ---------------- weight transpose + fp32->bf16 ----------------
// W [K,N] fp32 -> WT [N,K] bf16 (generic, for W1/W2)
__global__ __launch_bounds__(256)
void wtrans_kernel(const float* __restrict__ W, u16* __restrict__ WT, int K, int N) {
  __shared__ float tile[32][33];
  int tx = threadIdx.x & 31, ty = threadIdx.x >> 5;
  int n0 = blockIdx.x * 32, k0 = blockIdx.y * 32;
#pragma unroll
  for (int i = 0; i < 32; i += 8)
    tile[ty + i][tx] = W[(size_t)(k0 + ty + i) * N + (n0 + tx)];
  __syncthreads();
#pragma unroll
  for (int i = 0; i < 32; i += 8)
    WT[(size_t)(n0 + ty + i) * K + (k0 + tx)] = f2bf(tile[tx][ty + i]);
}

// 4 square [1024x1024] weights in one dispatch: z=0..2 -> WqkvT rows, z=3 -> WoT
__global__ __launch_bounds__(256)
void wtrans4_kernel(const float* __restrict__ W0, const float* __restrict__ W1_,
                    const float* __restrict__ W2_, const float* __restrict__ W3,
                    u16* __restrict__ Dqkv, u16* __restrict__ Do) {
  __shared__ float tile[32][33];
  int z = blockIdx.z;
  const float* W = (z == 0) ? W0 : (z == 1) ? W1_ : (z == 2) ? W2_ : W3;
  u16* D = (z < 3) ? (Dqkv + (size_t)z * EMB * EMB) : Do;
  int tx = threadIdx.x & 31, ty = threadIdx.x >> 5;
  int n0 = blockIdx.x * 32, k0 = blockIdx.y * 32;
#pragma unroll
  for (int i = 0; i < 32; i += 8)
    tile[ty + i][tx] = W[(size_t)(k0 + ty + i) * EMB + (n0 + tx)];
  __syncthreads();
#pragma unroll
  for (int i = 0; i < 32; i += 8)
    D[(size_t)(n0 + ty + i) * EMB + (k0 + tx)] = f2bf(tile[tx][ty + i]);
}

// ---------------- V transpose per head: QKV [B*S,3072] (V at col 2048+h*64)
// -> Vt [B*H, 64, SEQ]
__global__ __launch_bounds__(256)
void vtrans_kernel(const u16* __restrict__ QKV, u16* __restrict__ Vt) {
  __shared__ u16 tile[64 * 72];
  int bh = blockIdx.y, b = bh >> 4, h = bh & 15;
  int s0 = blockIdx.x * 64;
  const u16* src = QKV + (size_t)b * SEQ * QKVLD + 2048 + (size_t)h * HDIM;
  int tid = threadIdx.x;
#pragma unroll
  for (int cc = 0; cc < 2; ++cc) {
    int c = tid + cc * 256;
    int s = c >> 3, d0 = (c & 7) * 8;
    uint4 v = *(const uint4*)(src + (size_t)(s0 + s) * QKVLD + d0);
    *(uint4*)(&tile[s * 72 + d0]) = v;
  }
  __syncthreads();
  u16* dst = Vt + (size_t)bh * HDIM * SEQ;
#pragma unroll
  for (int cc = 0; cc < 2; ++cc) {
    int c = tid + cc * 256;
    int d = c >> 3, t0l = (c & 7) * 8;
    union { uint4 u; u16 s[8]; } ou;
#pragma unroll
    for (int j = 0; j < 8; ++j) ou.s[j] = tile[(t0l + j) * 72 + d];
    *(uint4*)(dst + (size_t)d * SEQ + s0 + t0l) = ou.u;
  }
}

// ---------------- layernorm: 1 row per wave, 4 rows per block ----------------
__global__ __launch_bounds__(256)
void ln_kernel(const float* __restrict__ in, const float* __restrict__ gamma,
               const float* __restrict__ beta, u16* __restrict__ outb) {
  int w = threadIdx.x >> 6, lane = threadIdx.x & 63;
  int row = blockIdx.x * 4 + w;
  size_t base = (size_t)row * EMB;
  float4 v[4];
  float s = 0.f, q = 0.f;
#pragma unroll
  for (int j = 0; j < 4; ++j) {
    v[j] = *(const float4*)(in + base + j * 256 + lane * 4);
    s += v[j].x + v[j].y + v[j].z + v[j].w;
    q += v[j].x * v[j].x + v[j].y * v[j].y + v[j].z * v[j].z + v[j].w * v[j].w;
  }
#pragma unroll
  for (int off = 1; off < 64; off <<= 1) {
    s += __shfl_xor(s, off);
    q += __shfl_xor(q, off);
  }
  float mean = s * (1.0f / EMB);
  float var = q * (1.0f / EMB) - mean * mean;
  float rstd = rsqrtf(var + 1e-5f);
#pragma unroll
  for (int j = 0; j < 4; ++j) {
    int c = j * 256 + lane * 4;
    float4 g4 = *(const float4*)(gamma + c);
    float4 b4 = *(const float4*)(beta + c);
    ushort4 ob;
    ob.x = f2bf((v[j].x - mean) * rstd * g4.x + b4.x);
    ob.y = f2bf((v[j].y - mean) * rstd * g4.y + b4.y);
    ob.z = f2bf((v[j].z - mean) * rstd * g4.z + b4.z);
    ob.w = f2bf((v[j].w - mean) * rstd * g4.w + b4.w);
    *(ushort4*)(outb + base + c) = ob;
  }
}

// ---------------- LN2 fused with Wo split-K reduce ----------------
// in = p[0]+p[pstride]+bias(col)+resid; layernorm(in) -> bf16 + fp32
__global__ __launch_bounds__(256)
void ln2f_kernel(const float* __restrict__ p, size_t pstride,
                 const float* __restrict__ bias, const float* __restrict__ resid,
                 const float* __restrict__ gamma, const float* __restrict__ beta,
                 u16* __restrict__ outb, float* __restrict__ outf) {
  int w = threadIdx.x >> 6, lane = threadIdx.x & 63;
  int row = blockIdx.x * 4 + w;
  size_t base = (size_t)row * EMB;
  float4 v[4];
  float s = 0.f, q = 0.f;
#pragma unroll
  for (int j = 0; j < 4; ++j) {
    int c = j * 256 + lane * 4;
    float4 a = *(const float4*)(p + base + c);
    float4 b = *(const float4*)(p + pstride + base + c);
    float4 r = *(const float4*)(resid + base + c);
    float4 bb = *(const float4*)(bias + c);
    v[j].x = a.x + b.x + r.x + bb.x;
    v[j].y = a.y + b.y + r.y + bb.y;
    v[j].z = a.z + b.z + r.z + bb.z;
    v[j].w = a.w + b.w + r.w + bb.w;
    s += v[j].x + v[j].y + v[j].z + v[j].w;
    q += v[j].x * v[j].x + v[j].y * v[j].y + v[j].z * v[j].z + v[j].w * v[j].w;
  }
#pragma unroll
  for (int off = 1; off < 64; off <<= 1) {
    s += __shfl_xor(s, off);
    q += __shfl_xor(q, off);
  }
  float mean = s * (1.0f / EMB);
  float var = q * (1.0f / EMB) - mean * mean;
  float rstd = rsqrtf(var + 1e-5f);
#pragma unroll
  for (int j = 0; j < 4; ++j) {
    int c = j * 256 + lane * 4;
    float4 g4 = *(const float4*)(gamma + c);
    float4 b4 = *(const float4*)(beta + c);
    float y0 = (v[j].x - mean) * rstd * g4.x + b4.x;
    float y1 = (v[j].y - mean) * rstd * g4.y + b4.y;
    float y2 = (v[j].z - mean) * rstd * g4.z + b4.z;
    float y3 = (v[j].w - mean) * rstd * g4.w + b4.w;
    ushort4 ob;
    ob.x = f2bf(y0); ob.y = f2bf(y1); ob.z = f2bf(y2); ob.w = f2bf(y3);
    *(ushort4*)(outb + base + c) = ob;
    *(float4*)(outf + base + c) = make_float4(y0, y1, y2, y3);
  }
}

// ---------------- split-K reduce: out = p[z0]+p[z1]+bias+resid (fp32) --------
__global__ __launch_bounds__(256)
void reduce2_kernel(const float* __restrict__ p, size_t pstride,
                    const float* __restrict__ bias, const float* __restrict__ resid,
                    float* __restrict__ out, int ncols) {
  size_t i = ((size_t)blockIdx.x * 256 + threadIdx.x) * 4;
  float4 a = *(const float4*)(p + i);
  float4 b = *(const float4*)(p + pstride + i);
  float4 r = *(const float4*)(resid + i);
  int col = (int)(i & (size_t)(ncols - 1));
  float4 bb = *(const float4*)(bias + col);
  float4 o;
  o.x = a.x + b.x + r.x + bb.x;
  o.y = a.y + b.y + r.y + bb.y;
  o.z = a.z + b.z + r.z + bb.z;
  o.w = a.w + b.w + r.w + bb.w;
  *(float4*)(out + i) = o;
}

// ---------------- GEMM (round-0 structure): C[M,N] = A*BT^T, 128x128 tile ----
// 256 threads, 32KB LDS -> 4 resident blocks/CU; per-K-step full drain is
// hidden by cross-block overlap (m114 mechanism).  + row-chunk XCD swizzle.
__global__ __launch_bounds__(256)
void gemm_bt(const u16* __restrict__ A, const u16* __restrict__ BT,
             const float* __restrict__ bias, const float* __restrict__ bias2,
             const float* __restrict__ bias3, void* __restrict__ out,
             const float* __restrict__ resid, int M, int N, int K,
             int mode, float scale, int ksplit,
             float* __restrict__ partial, size_t pstride) {
  __shared__ __align__(16) u16 As[128 * 64];
  __shared__ __align__(16) u16 Bs[128 * 64];
  int tid = threadIdx.x;
  int lane = tid & 63, w = tid >> 6;
  int wm = w >> 1, wn = w & 1;
  int g = lane >> 4, lr = lane & 15;
  int bx, by;
  xcd_swizzle(gridDim.x, gridDim.y, bx, by);
  int m0 = by * 128, n0 = bx * 128;
  int z = blockIdx.z;
  int kbeg = z * ksplit, kend = kbeg + ksplit;

  f32x4 acc[4][4];
#pragma unroll
  for (int mt = 0; mt < 4; ++mt)
#pragma unroll
    for (int nt = 0; nt < 4; ++nt) {
      acc[mt][nt][0] = 0.f; acc[mt][nt][1] = 0.f;
      acc[mt][nt][2] = 0.f; acc[mt][nt][3] = 0.f;
    }

  size_t ao[4], bo_[4];
  int lo[4];
#pragma unroll
  for (int cc = 0; cc < 4; ++cc) {
    int c = tid + cc * 256;
    int row = c >> 3, slot = c & 7;
    int gc = slot ^ (row & 7);
    ao[cc] = (size_t)(m0 + row) * K + gc * 8;
    bo_[cc] = (size_t)(n0 + row) * K + gc * 8;
    lo[cc] = c * 8;
  }
  int swz[2];
#pragma unroll
  for (int kk = 0; kk < 2; ++kk) swz[kk] = ((kk * 4 + g) ^ (lr & 7)) * 8;

  for (int k0 = kbeg; k0 < kend; k0 += 64) {
    __syncthreads();
#pragma unroll
    for (int cc = 0; cc < 4; ++cc) gload16(A + ao[cc] + k0, As + lo[cc]);
#pragma unroll
    for (int cc = 0; cc < 4; ++cc) gload16(BT + bo_[cc] + k0, Bs + lo[cc]);
    __syncthreads();
#pragma unroll
    for (int kk = 0; kk < 2; ++kk) {
      bf16x8 af[4], bfr[4];
#pragma unroll
      for (int mt = 0; mt < 4; ++mt)
        af[mt] = *(const bf16x8*)(As + (wm * 64 + mt * 16 + lr) * 64 + swz[kk]);
#pragma unroll
      for (int nt = 0; nt < 4; ++nt)
        bfr[nt] = *(const bf16x8*)(Bs + (wn * 64 + nt * 16 + lr) * 64 + swz[kk]);
#pragma unroll
      for (int mt = 0; mt < 4; ++mt)
#pragma unroll
        for (int nt = 0; nt < 4; ++nt)
          acc[mt][nt] = __builtin_amdgcn_mfma_f32_16x16x32_bf16(af[mt], bfr[nt], acc[mt][nt], 0, 0, 0);
    }
  }

  float* pz = partial + (size_t)z * pstride;
#pragma unroll
  for (int mt = 0; mt < 4; ++mt) {
    int row = m0 + wm * 64 + mt * 16 + g * 4;
#pragma unroll
    for (int nt = 0; nt < 4; ++nt) {
      int col = n0 + wn * 64 + nt * 16 + lr;
      float bcol;
      if (mode == 3) {
        int which = col >> 10;
        const float* bp = (which == 0) ? bias : (which == 1) ? bias2 : bias3;
        bcol = bp[col & 1023];
      } else if (mode != 4) {
        bcol = bias[col];
      } else {
        bcol = 0.f;
      }
#pragma unroll
      for (int r = 0; r < 4; ++r) {
        float vacc = acc[mt][nt][r] + bcol;
        size_t idx = (size_t)(row + r) * N + col;
        if (mode == 0)      ((u16*)out)[idx] = f2bf(vacc * scale);
        else if (mode == 1) ((u16*)out)[idx] = f2bf(geluf(vacc));
        else if (mode == 2) ((float*)out)[idx] = vacc + resid[idx];
        else if (mode == 3) ((u16*)out)[idx] = f2bf(col < 1024 ? vacc * QSCALE : vacc);
        else                pz[idx] = vacc;
      }
    }
  }
}

// ====================================================================
// gemm4p<BM>: BMx256 tile, BK=64, 512 threads (8 waves, 2M x 4N),
// **4-phase / 2-K-tile** counted-vmcnt ring with ONE barrier per phase.
// Round-9 theory: per-phase cost measured 2420 cy vs 824 for the identical
// 8-phase instruction mix (m201) -> overhead is per-phase/per-barrier, so
// merge (buf,kk) into one phase (MT x 4 MFMA) and drop the pre-MFMA barrier:
// with a 3-phase stage->read lag, the end-of-phase {vmcnt(2L) -> s_barrier}
// alone carries RAW (stages from phase p-2 drained at end of p, read at p+1)
// and WAR (reads of a region complete before that phase's end barrier; its
// overwrite is issued >=1 phase later).  Barriers/iter: 16 -> 4.
//
// Reads: ph0:(b0,k0) ph1:(b0,k1) ph2:(b1,k0) ph3:(b1,k1), tiles (2it, 2it+1).
// Stages (A+B of one region, L=RA+2 loads/thread): ph0:(b1,k1)<-2it+1,
// ph1:(b0,k0)<-2it+2, ph2:(b0,k1)<-2it+2, ph3:(b1,k0)<-2it+3.
// Prologue: (b0,k0),(b0,k1)<-t0, (b1,k0)<-t1; vmcnt(2L); barrier.
// Peeled last pair: ph0 stages (b1,k1)<-nk-1; then vmcnt 2L -> L -> 0.
// ====================================================================

#define BARM __builtin_amdgcn_s_barrier()
#define NOSTG ((void)0)
#define NOWT ((void)0)

#define STG_A(t, d, kh)                                                       \
  { _Pragma("unroll")                                                         \
    for (int j = 0; j < RA; ++j)                                              \
      gload16(A + (size_t)sgA[j] + kbeg + (t) * 64 + (kh) * 32,               \
              As + ((d) * 2 + (kh)) * ABUF + slA[j]); }

#define STG_B(t, d, kh)                                                       \
  { _Pragma("unroll")                                                         \
    for (int j = 0; j < 2; ++j)                                               \
      gload16(BT + (size_t)sgB[j] + kbeg + (t) * 64 + (kh) * 32,              \
              Bs + ((d) * 2 + (kh)) * 8192 + slB[j]); }

#define STG_R(t, d, kh) { STG_B(t, d, kh); STG_A(t, d, kh); }

#define VM2L asm volatile("s_waitcnt vmcnt(%0)" ::"n"(2 * (RA + 2)))
#define VM1L asm volatile("s_waitcnt vmcnt(%0)" ::"n"(RA + 2))
#define VMW0 asm volatile("s_waitcnt vmcnt(0)")

#define PHASE4(d, kk, STAGE, WAITC)                                           \
  {                                                                           \
    const u32 bA = bB + ((d) * 2 + (kk)) * 16384;                             \
    const u32 aA = aB + ((d) * 2 + (kk)) * (ABUF * 2);                        \
    bfr[0] = dsr16<0>(bA);                                                    \
    bfr[1] = dsr16<1024>(bA);                                                 \
    bfr[2] = dsr16<2048>(bA);                                                 \
    bfr[3] = dsr16<3072>(bA);                                                 \
    bf16x8 af[MT];                                                            \
    af[0] = dsr16<0>(aA);                                                     \
    af[1] = dsr16<1024>(aA);                                                  \
    af[2] = dsr16<2048>(aA);                                                  \
    af[3] = dsr16<3072>(aA);                                                  \
    if constexpr (MT > 4) {                                                   \
      af[4] = dsr16<4096>(aA);                                                \
      af[5] = dsr16<5120>(aA);                                                \
      af[6] = dsr16<6144>(aA);                                                \
      af[7] = dsr16<7168>(aA);                                                \
    }                                                                         \
    STAGE;                                                                    \
    asm volatile("s_waitcnt lgkmcnt(0)");                                     \
    __builtin_amdgcn_sched_barrier(0);                                        \
    __builtin_amdgcn_s_setprio(1);                                            \
    _Pragma("unroll")                                                         \
    for (int mi = 0; mi < MT; ++mi)                                           \
      _Pragma("unroll")                                                       \
      for (int nt = 0; nt < 4; ++nt)                                          \
        acc[mi][nt] = __builtin_amdgcn_mfma_f32_16x16x32_bf16(                \
            af[mi], bfr[nt], acc[mi][nt], 0, 0, 0);                           \
    __builtin_amdgcn_s_setprio(0);                                            \
    WAITC;                                                                    \
    BARM;                                                                     \
  }

template <int BM>
__global__ __launch_bounds__(512, 2)
void gemm4p(const u16* __restrict__ A, const u16* __restrict__ BT,
            const float* __restrict__ bias, const float* __restrict__ bias2,
            const float* __restrict__ bias3, void* __restrict__ out,
            const float* __restrict__ resid, int M, int N, int K,
            int mode, float scale, int ksplit,
            float* __restrict__ partial, size_t pstride) {
  constexpr int MT = BM / 32;   // 16-row m-frags per wave
  constexpr int RA = BM / 128;  // gload16 per A half-tile per thread
  constexpr int ABUF = BM * 32; // u16 per A (d,kh) sub-buffer
  __shared__ __align__(16) u16 As[4 * ABUF];
  __shared__ __align__(16) u16 Bs[4 * 8192];

  int tid = threadIdx.x;
  int lane = tid & 63, w = tid >> 6;
  int wm = w >> 2, wn = w & 3;
  int g = lane >> 4, lr = lane & 15;
  int bx, by;
  xcd_swizzle(gridDim.x, gridDim.y, bx, by);
  int m0 = by * BM, n0 = bx * 256;
  int z = blockIdx.z;
  size_t kbeg = (size_t)z * ksplit;
  int nk = ksplit >> 6, npair = nk >> 1;

  // frag ds_read offsets (u16 units); phys slot is a pure lane function
  int phys = ((lr & 1) * 4 + g) ^ ((lr >> 1) & 7);
  int aoff = wm * (BM / 2) * 32 + (lr >> 1) * 64 + phys * 8;
  int boff = wn * 2048 + (lr >> 1) * 64 + phys * 8;
  const u32 aB = lds_addr(As) + 2 * aoff;
  const u32 bB = lds_addr(Bs) + 2 * boff;

  // staging precompute: LDS linear (c*16B), global pre-swizzled (paired-row)
  int sgA[RA], slA[RA];
#pragma unroll
  for (int j = 0; j < RA; ++j) {
    int c = tid + j * 512;
    int sr = c >> 3, ph = c & 7, l = ph ^ (sr & 7);
    sgA[j] = (m0 + 2 * sr + (l >> 2)) * K + (l & 3) * 8;
    slA[j] = c * 8;
  }
  int sgB[2], slB[2];
#pragma unroll
  for (int j = 0; j < 2; ++j) {
    int c = tid + j * 512;
    int sr = c >> 3, ph = c & 7, l = ph ^ (sr & 7);
    sgB[j] = (n0 + 2 * sr + (l >> 2)) * K + (l & 3) * 8;
    slB[j] = c * 8;
  }

  f32x4 acc[MT][4];
#pragma unroll
  for (int mt = 0; mt < MT; ++mt)
#pragma unroll
    for (int nt = 0; nt < 4; ++nt) {
      acc[mt][nt][0] = 0.f; acc[mt][nt][1] = 0.f;
      acc[mt][nt][2] = 0.f; acc[mt][nt][3] = 0.f;
    }

  bf16x8 bfr[4];

  // prologue: (b0,k0),(b0,k1) <- t0; (b1,k0) <- t1; confirm (b0,k0)
  STG_R(0, 0, 0); STG_R(0, 0, 1); STG_R(1, 1, 0);
  VM2L; BARM;

  for (int it = 0; it < npair - 1; ++it) {
    int t1 = 2 * it + 1, t2 = 2 * it + 2, t3 = 2 * it + 3;
    PHASE4(0, 0, STG_R(t1, 1, 1), VM2L)
    PHASE4(0, 1, STG_R(t2, 0, 0), VM2L)
    PHASE4(1, 0, STG_R(t2, 0, 1), VM2L)
    PHASE4(1, 1, STG_R(t3, 1, 0), VM2L)
  }
  {  // peeled last pair: only (b1,k1)<-nk-1 left to issue
    int t1 = nk - 1;
    PHASE4(0, 0, STG_R(t1, 1, 1), VM2L)
    PHASE4(0, 1, NOSTG, VM1L)
    PHASE4(1, 0, NOSTG, VMW0)
    PHASE4(1, 1, NOSTG, NOWT)
  }

  // epilogue
  float* pz = partial + (size_t)z * pstride;
#pragma unroll
  for (int mt = 0; mt < MT; ++mt) {
    int row = m0 + wm * (BM / 2) + mt * 16 + g * 4;
#pragma unroll
    for (int nt = 0; nt < 4; ++nt) {
      int col = n0 + wn * 64 + nt * 16 + lr;
      float bcol;
      if (mode == 3) {
        int which = col >> 10;
        const float* bp = (which == 0) ? bias : (which == 1) ? bias2 : bias3;
        bcol = bp[col & 1023];
      } else if (mode != 4) {
        bcol = bias[col];
      } else {
        bcol = 0.f;
      }
#pragma unroll
      for (int r = 0; r < 4; ++r) {
        float vacc = acc[mt][nt][r] + bcol;
        size_t idx = (size_t)(row + r) * N + col;
        if (mode == 0)      ((u16*)out)[idx] = f2bf(vacc * scale);
        else if (mode == 1) ((u16*)out)[idx] = f2bf(geluf(vacc));
        else if (mode == 2) ((float*)out)[idx] = vacc + resid[idx];
        else if (mode == 3) ((u16*)out)[idx] = f2bf(col < 1024 ? vacc * QSCALE : vacc);
        else                pz[idx] = vacc;
      }
    }
  }
}

// ---------------- flash attention, paired q-tiles, no-max exp2 softmax -------
// (round-5 known-good structure)
__shared__ __align__(16) u16 attn_Kt[64 * 64];
__shared__ __align__(16) u16 attn_VT[64 * 64];
__shared__ __align__(16) u16 attn_Pw[2][4][16 * PWS];

template <int S0>
__device__ __forceinline__ void attn_tile(
    int t0, const int* q0, int w, int g, int lr, const bf16x8& ones,
    bf16x8 (&qf)[2][2], f32x4 (&lacc)[2], f32x4 (&oacc)[2][4]) {
  f32x4 sacc[2][4];
#pragma unroll
  for (int s = S0; s < 2; ++s)
#pragma unroll
    for (int nt = 0; nt < 4; ++nt) {
      sacc[s][nt][0] = 0.f; sacc[s][nt][1] = 0.f;
      sacc[s][nt][2] = 0.f; sacc[s][nt][3] = 0.f;
    }
#pragma unroll
  for (int kk = 0; kk < 2; ++kk)
#pragma unroll
    for (int nt = 0; nt < 4; ++nt) {
      int sw = ((kk * 4 + g) ^ lr) & 7;
      bf16x8 bfr = *(const bf16x8*)(&attn_Kt[(nt * 16 + lr) * 64 + sw * 8]);
      if (S0 == 0)
        sacc[0][nt] = __builtin_amdgcn_mfma_f32_16x16x32_bf16(qf[0][kk], bfr, sacc[0][nt], 0, 0, 0);
      sacc[1][nt] = __builtin_amdgcn_mfma_f32_16x16x32_bf16(qf[1][kk], bfr, sacc[1][nt], 0, 0, 0);
    }

#pragma unroll
  for (int s = S0; s < 2; ++s) {
    bool diag = (t0 == q0[s]);  // wave-uniform
#pragma unroll
    for (int r = 0; r < 4; ++r) {
#pragma unroll
      for (int nt = 0; nt < 4; ++nt) {
        float pv = ex2(sacc[s][nt][r]);
        if (diag && (nt * 16 + lr > w * 16 + g * 4 + r)) pv = 0.f;
        attn_Pw[s][w][(g * 4 + r) * PWS + nt * 16 + lr] = f2bf(pv);
      }
    }
  }

#pragma unroll
  for (int kk = 0; kk < 2; ++kk) {
    bf16x8 pf0, pf1;
    if (S0 == 0) pf0 = *(const bf16x8*)(&attn_Pw[0][w][lr * PWS + kk * 32 + g * 8]);
    pf1 = *(const bf16x8*)(&attn_Pw[1][w][lr * PWS + kk * 32 + g * 8]);
#pragma unroll
    for (int nt = 0; nt < 4; ++nt) {
      int sw = ((kk * 4 + g) ^ lr) & 7;
      bf16x8 vf = *(const bf16x8*)(&attn_VT[(nt * 16 + lr) * 64 + sw * 8]);
      if (S0 == 0)
        oacc[0][nt] = __builtin_amdgcn_mfma_f32_16x16x32_bf16(pf0, vf, oacc[0][nt], 0, 0, 0);
      oacc[1][nt] = __builtin_amdgcn_mfma_f32_16x16x32_bf16(pf1, vf, oacc[1][nt], 0, 0, 0);
    }
    if (S0 == 0)
      lacc[0] = __builtin_amdgcn_mfma_f32_16x16x32_bf16(pf0, ones, lacc[0], 0, 0, 0);
    lacc[1] = __builtin_amdgcn_mfma_f32_16x16x32_bf16(pf1, ones, lacc[1], 0, 0, 0);
  }
}

__global__ __launch_bounds__(256)
void attn2_kernel(const u16* __restrict__ QKV, const u16* __restrict__ Vt,
                  u16* __restrict__ ctx) {
  int tid = threadIdx.x, lane = tid & 63, w = tid >> 6;
  int g = lane >> 4, lr = lane & 15;
  int bh = blockIdx.y, b = bh >> 4, h = bh & 15;
  int q0[2];
  q0[0] = blockIdx.x * 64;
  q0[1] = (SEQ / 64 - 1 - blockIdx.x) * 64;
  const u16* Qh = QKV + (size_t)b * SEQ * QKVLD + (size_t)h * HDIM;
  const u16* Kh = Qh + 1024;
  const u16* Vth = Vt + (size_t)bh * HDIM * SEQ;

  bf16x8 ones;
#pragma unroll
  for (int j = 0; j < 8; ++j) ones[j] = (__bf16)1.0f;

  bf16x8 qf[2][2];
#pragma unroll
  for (int s = 0; s < 2; ++s)
#pragma unroll
    for (int kk = 0; kk < 2; ++kk)
      qf[s][kk] = *(const bf16x8*)(Qh + (size_t)(q0[s] + w * 16 + lr) * QKVLD + kk * 32 + g * 8);

  f32x4 lacc[2];
  f32x4 oacc[2][4];
#pragma unroll
  for (int s = 0; s < 2; ++s) {
    lacc[s][0] = 0.f; lacc[s][1] = 0.f; lacc[s][2] = 0.f; lacc[s][3] = 0.f;
#pragma unroll
    for (int nt = 0; nt < 4; ++nt) {
      oacc[s][nt][0] = 0.f; oacc[s][nt][1] = 0.f;
      oacc[s][nt][2] = 0.f; oacc[s][nt][3] = 0.f;
    }
  }

  int c1 = tid, c2 = tid + 256;
  int t1 = c1 >> 3, ch1 = (c1 ^ t1) & 7;
  int t2 = c2 >> 3, ch2 = (c2 ^ t2) & 7;
  for (int t0 = 0; t0 <= q0[1]; t0 += 64) {
    __syncthreads();
    gload16(Kh + (size_t)(t0 + t1) * QKVLD + ch1 * 8, attn_Kt + c1 * 8);
    gload16(Kh + (size_t)(t0 + t2) * QKVLD + ch2 * 8, attn_Kt + c2 * 8);
    gload16(Vth + (size_t)t1 * SEQ + t0 + ch1 * 8, attn_VT + c1 * 8);
    gload16(Vth + (size_t)t2 * SEQ + t0 + ch2 * 8, attn_VT + c2 * 8);
    __syncthreads();

    if (t0 <= q0[0])
      attn_tile<0>(t0, q0, w, g, lr, ones, qf, lacc, oacc);
    else
      attn_tile<1>(t0, q0, w, g, lr, ones, qf, lacc, oacc);
  }

#pragma unroll
  for (int s = 0; s < 2; ++s) {
    int srow = q0[s] + w * 16 + g * 4;
    float inv[4];
#pragma unroll
    for (int r = 0; r < 4; ++r) inv[r] = 1.0f / lacc[s][r];
#pragma unroll
    for (int nt = 0; nt < 4; ++nt) {
      int col = h * HDIM + nt * 16 + lr;
#pragma unroll
      for (int r = 0; r < 4; ++r) {
        float o = oacc[s][nt][r] * inv[r];
        ctx[((size_t)b * SEQ + srow + r) * EMB + col] = f2bf(o);
      }
    }
  }
}

// ---------------- launch ----------------
extern "C" void kernel_launch(void* const* d_in, const int* in_sizes, int n_in,
                              void* d_out, int out_size, void* d_ws, size_t ws_size,
                              hipStream_t stream) {
  const float* x    = (const float*)d_in[0];
  const float* Wq   = (const float*)d_in[2];
  const float* bq   = (const float*)d_in[3];
  const float* Wk   = (const float*)d_in[4];
  const float* bk   = (const float*)d_in[5];
  const float* Wv   = (const float*)d_in[6];
  const float* bv   = (const float*)d_in[7];
  const float* Wo   = (const float*)d_in[8];
  const float* bo   = (const float*)d_in[9];
  const float* W1   = (const float*)d_in[10];
  const float* b1   = (const float*)d_in[11];
  const float* W2   = (const float*)d_in[12];
  const float* b2   = (const float*)d_in[13];
  const float* ln1g = (const float*)d_in[14];
  const float* ln1b = (const float*)d_in[15];
  const float* ln2g = (const float*)d_in[16];
  const float* ln2b = (const float*)d_in[17];

  char* ws = (char*)d_ws;
  u16* WqkvT = (u16*)(ws + ((size_t)0 << 20));
  u16* WoT   = (u16*)(ws + ((size_t)6 << 20));
  u16* W1T   = (u16*)(ws + ((size_t)8 << 20));
  u16* W2T   = (u16*)(ws + ((size_t)16 << 20));
  u16* xb    = (u16*)(ws + ((size_t)24 << 20));
  u16* QKVb  = (u16*)(ws + ((size_t)32 << 20));
  u16* ctxb  = (u16*)(ws + ((size_t)56 << 20));
  float* x2f = (float*)(ws + ((size_t)48 << 20));
  u16* x2b   = xb;
  u16* VtG   = (u16*)(ws + ((size_t)64 << 20));
  float* pWo = (float*)(ws + ((size_t)64 << 20));  // 2 x 16MB partials
  u16* h1    = (u16*)(ws + ((size_t)64 << 20));    // 32MB
  float* pF2 = (float*)(ws + ((size_t)0 << 20));   // z0 at 0-16; z1 at 32-48

  dim3 blk(256);
  dim3 blk512(512);
  const int M = NBATCH * SEQ; // 4096

  // weight transposes (fp32 -> bf16, [K,N] -> [N,K])
  wtrans4_kernel<<<dim3(32, 32, 4), blk, 0, stream>>>(Wq, Wk, Wv, Wo, WqkvT, WoT);
  wtrans_kernel<<<dim3(128, 32), blk, 0, stream>>>(W1, W1T, EMB, FFDIM);
  wtrans_kernel<<<dim3(32, 128), blk, 0, stream>>>(W2, W2T, FFDIM, EMB);

  // LN1
  ln_kernel<<<M / 4, blk, 0, stream>>>(x, ln1g, ln1b, xb);

  // fused QKV projection: gemm_bt (768 blocks, ~4 resident/CU) + XCD swizzle
  gemm_bt<<<dim3(QKVLD / 128, M / 128), blk, 0, stream>>>(
      xb, WqkvT, bq, bk, bv, QKVb, nullptr, M, QKVLD, EMB, 3, 1.0f, EMB, nullptr, 0);

  // V^T per head
  vtrans_kernel<<<dim3(SEQ / 64, NBATCH * NHEAD), blk, 0, stream>>>(QKVb, VtG);

  // attention (paired q-tiles: uniform 33 iterations/block)
  attn2_kernel<<<dim3(SEQ / 128, NBATCH * NHEAD), blk, 0, stream>>>(QKVb, VtG, ctxb);

  // output projection: gemm4p<128> split-K=2
  gemm4p<128><<<dim3(EMB / 256, M / 128, 2), blk512, 0, stream>>>(
      ctxb, WoT, nullptr, nullptr, nullptr, nullptr, nullptr, M, EMB, EMB, 4, 1.0f,
      EMB / 2, pWo, (size_t)4 << 20);

  // LN2 fused with Wo reduce (+bo+x residual) -> x2f fp32 + x2b bf16
  ln2f_kernel<<<M / 4, blk, 0, stream>>>(pWo, (size_t)4 << 20, bo, x, ln2g, ln2b,
                                         x2b, x2f);

  // FFN1 + fast GELU: gemm4p<256> (grid 16x16)
  gemm4p<256><<<dim3(FFDIM / 256, M / 256), blk512, 0, stream>>>(
      x2b, W1T, b1, nullptr, nullptr, h1, nullptr, M, FFDIM, EMB, 1, 1.0f, EMB,
      nullptr, 0);

  // FFN2: gemm4p<128> split-K=2
  gemm4p<128><<<dim3(EMB / 256, M / 128, 2), blk512, 0, stream>>>(
      h1, W2T, nullptr, nullptr, nullptr, nullptr, nullptr, M, EMB, FFDIM, 4, 1.0f,
      FFDIM / 2, pF2, (size_t)8 << 20);
  // d_out = p0 + p1 + b2 + x2f
  reduce2_kernel<<<M * EMB / 1024, blk, 0, stream>>>(pF2, (size_t)8 << 20, b2, x2f,
                                                     (float*)d_out, EMB);
}